// Round 1
// baseline (7239.132 us; speedup 1.0000x reference)
//
#include <hip/hip_runtime.h>
#include <math.h>

#define NN 100000
#define NE 800000
// DIM=128, HEADS=4, CH=32

typedef __attribute__((ext_vector_type(8))) short short8;
typedef __attribute__((ext_vector_type(4))) float f32x4;

__device__ __forceinline__ float bf2f(unsigned short u) {
  union { float f; unsigned int i; } x; x.i = ((unsigned int)u) << 16; return x.f;
}
__device__ __forceinline__ unsigned short f2bf(float f) {
  union { float f; unsigned int i; } x; x.f = f;
  unsigned int r = x.i + 0x7fffu + ((x.i >> 16) & 1u);
  return (unsigned short)(r >> 16);
}

__device__ __forceinline__ short8 load8_f32_as_bf16(const float* p) {
  const float4 a = *(const float4*)p;
  const float4 b = *(const float4*)(p + 4);
  short8 r;
  r[0] = (short)f2bf(a.x); r[1] = (short)f2bf(a.y); r[2] = (short)f2bf(a.z); r[3] = (short)f2bf(a.w);
  r[4] = (short)f2bf(b.x); r[5] = (short)f2bf(b.y); r[6] = (short)f2bf(b.z); r[7] = (short)f2bf(b.w);
  return r;
}

// ---- weight transpose + bf16 convert: wT[slot][n][k] = W[k][n] ----
// slots: 0..3 = Wq0,Wk0,Wv0,Ws0 ; 4..7 = Wq1,Wk1,Wv1,Ws1 ; 8,9 = We0,We1 ; 10 = Wo
__global__ __launch_bounds__(256) void conv_w(
    const float* __restrict__ Wq, const float* __restrict__ Wk, const float* __restrict__ Wv,
    const float* __restrict__ Ws, const float* __restrict__ We, const float* __restrict__ Wo,
    unsigned short* __restrict__ wT)
{
  int idx = blockIdx.x * 256 + threadIdx.x;   // 11*16384 total
  int m = idx >> 14;
  int r = idx & 16383;
  int n = r >> 7, kk = r & 127;
  const float* src;
  switch (m) {
    case 0: src = Wq; break;
    case 1: src = Wk; break;
    case 2: src = Wv; break;
    case 3: src = Ws; break;
    case 4: src = Wq + 16384; break;
    case 5: src = Wk + 16384; break;
    case 6: src = Wv + 16384; break;
    case 7: src = Ws + 16384; break;
    case 8: src = We; break;
    case 9: src = We + 16384; break;
    default: src = Wo; break;
  }
  wT[idx] = f2bf(src[(size_t)kk * 128 + n]);
}

// ---- q,k,v,skip projections: 4 GEMMs sharing the A tile ----
template<int ABF16>
__global__ __launch_bounds__(256) void qkvs_gemm(
    const void* __restrict__ Ap, const unsigned short* __restrict__ wT, int slot0,
    const float* __restrict__ bq, const float* __restrict__ bk,
    const float* __restrict__ bv, const float* __restrict__ bs,
    unsigned short* __restrict__ qo, unsigned short* __restrict__ ko,
    unsigned short* __restrict__ vo, unsigned short* __restrict__ so, int M)
{
  const int wave = threadIdx.x >> 6, lane = threadIdx.x & 63;
  const int row0 = blockIdx.x * 64 + wave * 16;
  int arow = row0 + (lane & 15);
  if (arow > M - 1) arow = M - 1;           // clamp: A row feeds only its own D row
  const int kgrp = (lane >> 4) * 8;

  f32x4 acc[4][8];
  #pragma unroll
  for (int w = 0; w < 4; w++)
    #pragma unroll
    for (int c = 0; c < 8; c++)
      #pragma unroll
      for (int j = 0; j < 4; j++) acc[w][c][j] = 0.f;

  const unsigned short* wts[4];
  #pragma unroll
  for (int w = 0; w < 4; w++) wts[w] = wT + (size_t)(slot0 + w) * 16384;

  #pragma unroll
  for (int kt = 0; kt < 4; ++kt) {
    const int kb = kt * 32 + kgrp;
    short8 a;
    if (ABF16) a = *(const short8*)((const unsigned short*)Ap + (size_t)arow * 128 + kb);
    else       a = load8_f32_as_bf16((const float*)Ap + (size_t)arow * 128 + kb);
    #pragma unroll
    for (int w = 0; w < 4; ++w) {
      #pragma unroll
      for (int c = 0; c < 8; ++c) {
        const int col = c * 16 + (lane & 15);
        short8 b = *(const short8*)(wts[w] + (size_t)col * 128 + kb);
        acc[w][c] = __builtin_amdgcn_mfma_f32_16x16x32_bf16(a, b, acc[w][c], 0, 0, 0);
      }
    }
  }

  const int colb = lane & 15;
  const int rsub = (lane >> 4) * 4;
  const float* biases[4] = { bq, bk, bv, bs };
  unsigned short* outs[4] = { qo, ko, vo, so };
  #pragma unroll
  for (int w = 0; w < 4; w++) {
    #pragma unroll
    for (int c = 0; c < 8; c++) {
      const int col = c * 16 + colb;
      const float bia = biases[w][col];
      #pragma unroll
      for (int j = 0; j < 4; j++) {
        const int row = row0 + rsub + j;
        if (row < M) outs[w][(size_t)row * 128 + col] = f2bf(acc[w][c][j] + bia);
      }
    }
  }
}

// ---- edge projection: e = edge_attr @ We (optionally both layers in one pass) ----
__global__ __launch_bounds__(256) void edge_gemm(
    const float* __restrict__ A, const unsigned short* __restrict__ wT, int s0, int s1,
    unsigned short* __restrict__ e0, unsigned short* __restrict__ e1, int M)
{
  const int wave = threadIdx.x >> 6, lane = threadIdx.x & 63;
  const int row0 = blockIdx.x * 64 + wave * 16;
  int arow = row0 + (lane & 15);
  if (arow > M - 1) arow = M - 1;
  const int kgrp = (lane >> 4) * 8;

  f32x4 acc0[8], acc1[8];
  #pragma unroll
  for (int c = 0; c < 8; c++)
    #pragma unroll
    for (int j = 0; j < 4; j++) { acc0[c][j] = 0.f; acc1[c][j] = 0.f; }

  const unsigned short* w0 = wT + (size_t)s0 * 16384;
  const unsigned short* w1 = wT + (size_t)(s1 < 0 ? s0 : s1) * 16384;

  #pragma unroll
  for (int kt = 0; kt < 4; ++kt) {
    const int kb = kt * 32 + kgrp;
    short8 a = load8_f32_as_bf16(A + (size_t)arow * 128 + kb);
    #pragma unroll
    for (int c = 0; c < 8; ++c) {
      const int col = c * 16 + (lane & 15);
      short8 b = *(const short8*)(w0 + (size_t)col * 128 + kb);
      acc0[c] = __builtin_amdgcn_mfma_f32_16x16x32_bf16(a, b, acc0[c], 0, 0, 0);
      if (e1) {
        short8 b2 = *(const short8*)(w1 + (size_t)col * 128 + kb);
        acc1[c] = __builtin_amdgcn_mfma_f32_16x16x32_bf16(a, b2, acc1[c], 0, 0, 0);
      }
    }
  }

  const int colb = lane & 15;
  const int rsub = (lane >> 4) * 4;
  #pragma unroll
  for (int c = 0; c < 8; c++) {
    const int col = c * 16 + colb;
    #pragma unroll
    for (int j = 0; j < 4; j++) {
      const int row = row0 + rsub + j;
      if (row < M) {
        e0[(size_t)row * 128 + col] = f2bf(acc0[c][j]);
        if (e1) e1[(size_t)row * 128 + col] = f2bf(acc1[c][j]);
      }
    }
  }
}

// ---- single-pass edge attention: p = exp(logit); agg += p*vj; denom += p ----
__global__ __launch_bounds__(256) void edge_attn(
    const int* __restrict__ ei, const unsigned short* __restrict__ e,
    const unsigned short* __restrict__ q, const unsigned short* __restrict__ k,
    const unsigned short* __restrict__ v, float* __restrict__ agg, float* __restrict__ denom)
{
  const int t = blockIdx.x * 256 + threadIdx.x;   // 16 lanes per edge
  const int eid = t >> 4;
  const int j = t & 15;                           // dims j*8 .. j*8+7, head = j>>2
  const int src = ei[eid];
  const int dst = ei[NE + eid];

  short8 ev = *(const short8*)(e + (size_t)eid * 128 + j * 8);
  short8 kv = *(const short8*)(k + (size_t)src * 128 + j * 8);
  short8 qv = *(const short8*)(q + (size_t)dst * 128 + j * 8);
  short8 vv = *(const short8*)(v + (size_t)src * 128 + j * 8);

  float vj[8];
  float dot = 0.f;
  #pragma unroll
  for (int i = 0; i < 8; i++) {
    float ee = bf2f((unsigned short)ev[i]);
    float kj = bf2f((unsigned short)kv[i]) + ee;
    vj[i] = bf2f((unsigned short)vv[i]) + ee;
    dot += bf2f((unsigned short)qv[i]) * kj;
  }
  dot += __shfl_xor(dot, 1, 64);
  dot += __shfl_xor(dot, 2, 64);
  const float p = expf(dot * 0.17677669529663687f);   // / sqrt(32)

  if ((j & 3) == 0) unsafeAtomicAdd(&denom[(size_t)dst * 4 + (j >> 2)], p);
  #pragma unroll
  for (int i = 0; i < 8; i++)
    unsafeAtomicAdd(&agg[(size_t)dst * 128 + j * 8 + i], p * vj[i]);
}

// ---- node epilogue: divide, beta-gate with skip, GELU, LayerNorm (+optional residual add) ----
__global__ __launch_bounds__(256) void node_post(
    const float* __restrict__ agg, const float* __restrict__ denom,
    const unsigned short* __restrict__ xr, const float* __restrict__ Wb,
    const float* __restrict__ lng, const float* __restrict__ lnb,
    const unsigned short* __restrict__ prev, unsigned short* __restrict__ hout)
{
  const int row = blockIdx.x * 4 + (threadIdx.x >> 6);
  const int lane = threadIdx.x & 63;
  const int d0 = lane * 2;
  const size_t base = (size_t)row * 128 + d0;

  const float den = denom[(size_t)row * 4 + (d0 >> 5)] + 1e-16f;
  float o0 = agg[base] / den, o1 = agg[base + 1] / den;
  float x0 = bf2f(xr[base]), x1 = bf2f(xr[base + 1]);

  float s = o0 * Wb[d0] + o1 * Wb[d0 + 1]
          + x0 * Wb[128 + d0] + x1 * Wb[129 + d0]
          + (o0 - x0) * Wb[256 + d0] + (o1 - x1) * Wb[257 + d0];
  #pragma unroll
  for (int off = 32; off >= 1; off >>= 1) s += __shfl_xor(s, off, 64);
  const float beta = 1.f / (1.f + expf(-s));

  float y0 = beta * x0 + (1.f - beta) * o0;
  float y1 = beta * x1 + (1.f - beta) * o1;
  y0 = 0.5f * y0 * (1.f + erff(y0 * 0.7071067811865475f));
  y1 = 0.5f * y1 * (1.f + erff(y1 * 0.7071067811865475f));

  float mu = y0 + y1;
  #pragma unroll
  for (int off = 32; off >= 1; off >>= 1) mu += __shfl_xor(mu, off, 64);
  mu *= (1.f / 128.f);
  float dv0 = y0 - mu, dv1 = y1 - mu;
  float var = dv0 * dv0 + dv1 * dv1;
  #pragma unroll
  for (int off = 32; off >= 1; off >>= 1) var += __shfl_xor(var, off, 64);
  var *= (1.f / 128.f);
  const float rs = rsqrtf(var + 1e-5f);

  float h0 = dv0 * rs * lng[d0] + lnb[d0];
  float h1 = dv1 * rs * lng[d0 + 1] + lnb[d0 + 1];
  if (prev) { h0 += bf2f(prev[base]); h1 += bf2f(prev[base + 1]); }
  hout[base] = f2bf(h0);
  hout[base + 1] = f2bf(h1);
}

// ---- g = sigmoid(x @ Wg + bg) ----
__global__ __launch_bounds__(256) void gate_kernel(
    const float* __restrict__ x, const float* __restrict__ Wg,
    const float* __restrict__ bg, float* __restrict__ g)
{
  const int row = blockIdx.x * 4 + (threadIdx.x >> 6);
  const int lane = threadIdx.x & 63;
  const size_t base = (size_t)row * 128 + lane * 2;
  float s = x[base] * Wg[lane * 2] + x[base + 1] * Wg[lane * 2 + 1];
  #pragma unroll
  for (int off = 32; off >= 1; off >>= 1) s += __shfl_xor(s, off, 64);
  g[row] = 1.f / (1.f + expf(-(s + bg[0])));
}

// ---- final: out = g*x + (1-g)*((h1+h2) @ Wo + bo) ----
__global__ __launch_bounds__(256) void final_gemm(
    const unsigned short* __restrict__ A, const unsigned short* __restrict__ wT,
    const float* __restrict__ bo, const float* __restrict__ xin,
    const float* __restrict__ g, float* __restrict__ out, int M)
{
  const int wave = threadIdx.x >> 6, lane = threadIdx.x & 63;
  const int row0 = blockIdx.x * 64 + wave * 16;
  int arow = row0 + (lane & 15);
  if (arow > M - 1) arow = M - 1;
  const int kgrp = (lane >> 4) * 8;

  f32x4 acc[8];
  #pragma unroll
  for (int c = 0; c < 8; c++)
    #pragma unroll
    for (int j = 0; j < 4; j++) acc[c][j] = 0.f;

  const unsigned short* wt = wT + (size_t)10 * 16384;
  #pragma unroll
  for (int kt = 0; kt < 4; ++kt) {
    const int kb = kt * 32 + kgrp;
    short8 a = *(const short8*)(A + (size_t)arow * 128 + kb);
    #pragma unroll
    for (int c = 0; c < 8; ++c) {
      const int col = c * 16 + (lane & 15);
      short8 b = *(const short8*)(wt + (size_t)col * 128 + kb);
      acc[c] = __builtin_amdgcn_mfma_f32_16x16x32_bf16(a, b, acc[c], 0, 0, 0);
    }
  }

  const int colb = lane & 15;
  const int rsub = (lane >> 4) * 4;
  float grow[4];
  #pragma unroll
  for (int j = 0; j < 4; j++) {
    const int row = row0 + rsub + j;
    grow[j] = (row < M) ? g[row] : 0.f;
  }
  #pragma unroll
  for (int c = 0; c < 8; c++) {
    const int col = c * 16 + colb;
    const float bia = bo[col];
    #pragma unroll
    for (int j = 0; j < 4; j++) {
      const int row = row0 + rsub + j;
      if (row < M) {
        const float o = acc[c][j] + bia;
        out[(size_t)row * 128 + col] = grow[j] * xin[(size_t)row * 128 + col] + (1.f - grow[j]) * o;
      }
    }
  }
}

extern "C" void kernel_launch(void* const* d_in, const int* in_sizes, int n_in,
                              void* d_out, int out_size, void* d_ws, size_t ws_size,
                              hipStream_t stream)
{
  const float* x  = (const float*)d_in[0];
  const int*   ei = (const int*)d_in[1];
  const float* ea = (const float*)d_in[2];
  const float* Wq = (const float*)d_in[3];
  const float* bq = (const float*)d_in[4];
  const float* Wk = (const float*)d_in[5];
  const float* bk = (const float*)d_in[6];
  const float* Wv = (const float*)d_in[7];
  const float* bv = (const float*)d_in[8];
  const float* We = (const float*)d_in[9];
  const float* Ws = (const float*)d_in[10];
  const float* bs = (const float*)d_in[11];
  const float* Wb = (const float*)d_in[12];
  const float* lng= (const float*)d_in[13];
  const float* lnb= (const float*)d_in[14];
  const float* Wo = (const float*)d_in[15];
  const float* bo = (const float*)d_in[16];
  const float* Wg = (const float*)d_in[17];
  const float* bg = (const float*)d_in[18];
  float* outp = (float*)d_out;

  char* p = (char*)d_ws;
  auto take = [&](size_t b) -> char* { char* r = p; p += (b + 255) & ~(size_t)255; return r; };
  unsigned short* wT = (unsigned short*)take((size_t)11 * 16384 * 2);
  unsigned short* q  = (unsigned short*)take((size_t)NN * 128 * 2);
  unsigned short* k  = (unsigned short*)take((size_t)NN * 128 * 2);
  unsigned short* v  = (unsigned short*)take((size_t)NN * 128 * 2);
  unsigned short* xr = (unsigned short*)take((size_t)NN * 128 * 2);
  unsigned short* h1 = (unsigned short*)take((size_t)NN * 128 * 2);
  unsigned short* hs = (unsigned short*)take((size_t)NN * 128 * 2);
  float* agg  = (float*)take((size_t)NN * 128 * 4);
  float* den  = (float*)take((size_t)NN * 4 * 4);
  float* gbuf = (float*)take((size_t)NN * 4);
  unsigned short* e0 = (unsigned short*)take((size_t)NE * 128 * 2);
  size_t used = (size_t)(p - (char*)d_ws);
  const bool dual = (used + (size_t)NE * 128 * 2) <= ws_size;
  unsigned short* e1 = dual ? (unsigned short*)take((size_t)NE * 128 * 2) : e0;

  conv_w<<<704, 256, 0, stream>>>(Wq, Wk, Wv, Ws, We, Wo, wT);
  if (dual) edge_gemm<<<12500, 256, 0, stream>>>(ea, wT, 8, 9, e0, e1, NE);
  else      edge_gemm<<<12500, 256, 0, stream>>>(ea, wT, 8, -1, e0, nullptr, NE);

  // layer 1
  hipMemsetAsync(agg, 0, (size_t)NN * 128 * 4, stream);
  hipMemsetAsync(den, 0, (size_t)NN * 16, stream);
  qkvs_gemm<0><<<1563, 256, 0, stream>>>(x, wT, 0, bq, bk, bv, bs, q, k, v, xr, NN);
  edge_attn<<<50000, 256, 0, stream>>>(ei, e0, q, k, v, agg, den);
  node_post<<<25000, 256, 0, stream>>>(agg, den, xr, Wb, lng, lnb, nullptr, h1);

  // layer 2
  if (!dual) edge_gemm<<<12500, 256, 0, stream>>>(ea, wT, 9, -1, e0, nullptr, NE);
  hipMemsetAsync(agg, 0, (size_t)NN * 128 * 4, stream);
  hipMemsetAsync(den, 0, (size_t)NN * 16, stream);
  qkvs_gemm<1><<<1563, 256, 0, stream>>>(h1, wT, 4, bq + 128, bk + 128, bv + 128, bs + 128, q, k, v, xr, NN);
  edge_attn<<<50000, 256, 0, stream>>>(ei, e1, q, k, v, agg, den);
  node_post<<<25000, 256, 0, stream>>>(agg, den, xr, Wb + 384, lng + 128, lnb + 128, h1, hs);

  // final
  gate_kernel<<<25000, 256, 0, stream>>>(x, Wg, bg, gbuf);
  final_gemm<<<1563, 256, 0, stream>>>(hs, wT, bo, x, gbuf, outp, NN);
}

// Round 2
// 1854.640 us; speedup vs baseline: 3.9033x; 3.9033x over previous
//
#include <hip/hip_runtime.h>
#include <math.h>

#define NN 100000
#define NE 800000
// DIM=128, HEADS=4, CH=32

typedef __attribute__((ext_vector_type(8))) short short8;
typedef __attribute__((ext_vector_type(4))) float f32x4;

__device__ __forceinline__ float bf2f(unsigned short u) {
  union { float f; unsigned int i; } x; x.i = ((unsigned int)u) << 16; return x.f;
}
__device__ __forceinline__ unsigned short f2bf(float f) {
  union { float f; unsigned int i; } x; x.f = f;
  unsigned int r = x.i + 0x7fffu + ((x.i >> 16) & 1u);
  return (unsigned short)(r >> 16);
}

__device__ __forceinline__ short8 load8_f32_as_bf16(const float* p) {
  const float4 a = *(const float4*)p;
  const float4 b = *(const float4*)(p + 4);
  short8 r;
  r[0] = (short)f2bf(a.x); r[1] = (short)f2bf(a.y); r[2] = (short)f2bf(a.z); r[3] = (short)f2bf(a.w);
  r[4] = (short)f2bf(b.x); r[5] = (short)f2bf(b.y); r[6] = (short)f2bf(b.z); r[7] = (short)f2bf(b.w);
  return r;
}

// ================= CSR build =================
__global__ __launch_bounds__(256) void hist_k(const int* __restrict__ ei, int* __restrict__ deg) {
  int t = blockIdx.x * 256 + threadIdx.x;
  if (t < NE) atomicAdd(&deg[ei[NE + t]], 1);
}

// block sums over chunks of 1024
__global__ __launch_bounds__(256) void scan1(const int* __restrict__ deg, int* __restrict__ bsum) {
  __shared__ int sd[256];
  const int b = blockIdx.x, t = threadIdx.x, base = b * 1024;
  int s = 0;
  #pragma unroll
  for (int i = 0; i < 4; i++) { int idx = base + t * 4 + i; if (idx < NN) s += deg[idx]; }
  sd[t] = s; __syncthreads();
  for (int off = 128; off >= 1; off >>= 1) { if (t < off) sd[t] += sd[t + off]; __syncthreads(); }
  if (t == 0) bsum[b] = sd[0];
}

__global__ void scan2(int* __restrict__ bsum, int nb, int* __restrict__ rowstart) {
  if (threadIdx.x == 0 && blockIdx.x == 0) {
    int run = 0;
    for (int i = 0; i < nb; i++) { int v = bsum[i]; bsum[i] = run; run += v; }
    rowstart[NN] = run;
  }
}

__global__ __launch_bounds__(256) void scan3(const int* __restrict__ deg, const int* __restrict__ bsum,
                                             int* __restrict__ rowstart, int* __restrict__ cursor) {
  __shared__ int sd[256];
  const int b = blockIdx.x, t = threadIdx.x, base = b * 1024;
  int vals[4]; int s = 0;
  #pragma unroll
  for (int i = 0; i < 4; i++) { int idx = base + t * 4 + i; vals[i] = (idx < NN) ? deg[idx] : 0; s += vals[i]; }
  sd[t] = s; __syncthreads();
  int excl = 0;
  for (int i = 0; i < t; i++) excl += sd[i];
  int run = bsum[b] + excl;
  #pragma unroll
  for (int i = 0; i < 4; i++) {
    int idx = base + t * 4 + i;
    if (idx < NN) { rowstart[idx] = run; cursor[idx] = run; run += vals[i]; }
  }
}

__global__ __launch_bounds__(256) void scatter_k(const int* __restrict__ ei, int* __restrict__ cursor,
                                                 int* __restrict__ sortpos, int* __restrict__ srcs) {
  int t = blockIdx.x * 256 + threadIdx.x;
  if (t >= NE) return;
  int dst = ei[NE + t];
  int pos = atomicAdd(&cursor[dst], 1);
  sortpos[t] = pos;
  srcs[pos] = ei[t];
}

// ================= weight prep =================
// slots: 0..3 = Wq0,Wk0,Wv0,Ws0 ; 4..7 = Wq1,Wk1,Wv1,Ws1 ; 8,9 = We0,We1 ; 10 = Wo
__global__ __launch_bounds__(256) void conv_w(
    const float* __restrict__ Wq, const float* __restrict__ Wk, const float* __restrict__ Wv,
    const float* __restrict__ Ws, const float* __restrict__ We, const float* __restrict__ Wo,
    unsigned short* __restrict__ wT)
{
  int idx = blockIdx.x * 256 + threadIdx.x;   // 11*16384 total
  int m = idx >> 14;
  int r = idx & 16383;
  int n = r >> 7, kk = r & 127;
  const float* src;
  switch (m) {
    case 0: src = Wq; break;
    case 1: src = Wk; break;
    case 2: src = Wv; break;
    case 3: src = Ws; break;
    case 4: src = Wq + 16384; break;
    case 5: src = Wk + 16384; break;
    case 6: src = Wv + 16384; break;
    case 7: src = Ws + 16384; break;
    case 8: src = We; break;
    case 9: src = We + 16384; break;
    default: src = Wo; break;
  }
  wT[idx] = f2bf(src[(size_t)kk * 128 + n]);
}

// ================= q,k,v,skip projections =================
template<int ABF16>
__global__ __launch_bounds__(256) void qkvs_gemm(
    const void* __restrict__ Ap, const unsigned short* __restrict__ wT, int slot0,
    const float* __restrict__ bq, const float* __restrict__ bk,
    const float* __restrict__ bv, const float* __restrict__ bs,
    unsigned short* __restrict__ qo, unsigned short* __restrict__ ko,
    unsigned short* __restrict__ vo, unsigned short* __restrict__ so, int M)
{
  const int wave = threadIdx.x >> 6, lane = threadIdx.x & 63;
  const int row0 = blockIdx.x * 64 + wave * 16;
  int arow = row0 + (lane & 15);
  if (arow > M - 1) arow = M - 1;
  const int kgrp = (lane >> 4) * 8;

  f32x4 acc[4][8];
  #pragma unroll
  for (int w = 0; w < 4; w++)
    #pragma unroll
    for (int c = 0; c < 8; c++)
      #pragma unroll
      for (int j = 0; j < 4; j++) acc[w][c][j] = 0.f;

  const unsigned short* wts[4];
  #pragma unroll
  for (int w = 0; w < 4; w++) wts[w] = wT + (size_t)(slot0 + w) * 16384;

  #pragma unroll
  for (int kt = 0; kt < 4; ++kt) {
    const int kb = kt * 32 + kgrp;
    short8 a;
    if (ABF16) a = *(const short8*)((const unsigned short*)Ap + (size_t)arow * 128 + kb);
    else       a = load8_f32_as_bf16((const float*)Ap + (size_t)arow * 128 + kb);
    #pragma unroll
    for (int w = 0; w < 4; ++w) {
      #pragma unroll
      for (int c = 0; c < 8; ++c) {
        const int col = c * 16 + (lane & 15);
        short8 b = *(const short8*)(wts[w] + (size_t)col * 128 + kb);
        acc[w][c] = __builtin_amdgcn_mfma_f32_16x16x32_bf16(a, b, acc[w][c], 0, 0, 0);
      }
    }
  }

  const int colb = lane & 15;
  const int rsub = (lane >> 4) * 4;
  const float* biases[4] = { bq, bk, bv, bs };
  unsigned short* outs[4] = { qo, ko, vo, so };
  #pragma unroll
  for (int w = 0; w < 4; w++) {
    #pragma unroll
    for (int c = 0; c < 8; c++) {
      const int col = c * 16 + colb;
      const float bia = biases[w][col];
      #pragma unroll
      for (int j = 0; j < 4; j++) {
        const int row = row0 + rsub + j;
        if (row < M) outs[w][(size_t)row * 128 + col] = f2bf(acc[w][c][j] + bia);
      }
    }
  }
}

// ================= edge projection, written in dst-sorted order =================
__global__ __launch_bounds__(256) void edge_gemm(
    const float* __restrict__ A, const unsigned short* __restrict__ wT, int s0, int s1,
    const int* __restrict__ sortpos,
    unsigned short* __restrict__ e0, unsigned short* __restrict__ e1, int M)
{
  const int wave = threadIdx.x >> 6, lane = threadIdx.x & 63;
  const int row0 = blockIdx.x * 64 + wave * 16;
  int arow = row0 + (lane & 15);
  if (arow > M - 1) arow = M - 1;
  const int kgrp = (lane >> 4) * 8;

  f32x4 acc0[8], acc1[8];
  #pragma unroll
  for (int c = 0; c < 8; c++)
    #pragma unroll
    for (int j = 0; j < 4; j++) { acc0[c][j] = 0.f; acc1[c][j] = 0.f; }

  const unsigned short* w0 = wT + (size_t)s0 * 16384;
  const unsigned short* w1 = wT + (size_t)(s1 < 0 ? s0 : s1) * 16384;

  #pragma unroll
  for (int kt = 0; kt < 4; ++kt) {
    const int kb = kt * 32 + kgrp;
    short8 a = load8_f32_as_bf16(A + (size_t)arow * 128 + kb);
    #pragma unroll
    for (int c = 0; c < 8; ++c) {
      const int col = c * 16 + (lane & 15);
      short8 b = *(const short8*)(w0 + (size_t)col * 128 + kb);
      acc0[c] = __builtin_amdgcn_mfma_f32_16x16x32_bf16(a, b, acc0[c], 0, 0, 0);
      if (e1) {
        short8 b2 = *(const short8*)(w1 + (size_t)col * 128 + kb);
        acc1[c] = __builtin_amdgcn_mfma_f32_16x16x32_bf16(a, b2, acc1[c], 0, 0, 0);
      }
    }
  }

  const int colb = lane & 15;
  const int rsub = (lane >> 4) * 4;
  int spos[4];
  #pragma unroll
  for (int j = 0; j < 4; j++) {
    const int row = row0 + rsub + j;
    spos[j] = (row < M) ? sortpos[row] : 0;
  }
  #pragma unroll
  for (int c = 0; c < 8; c++) {
    const int col = c * 16 + colb;
    #pragma unroll
    for (int j = 0; j < 4; j++) {
      const int row = row0 + rsub + j;
      if (row < M) {
        e0[(size_t)spos[j] * 128 + col] = f2bf(acc0[c][j]);
        if (e1) e1[(size_t)spos[j] * 128 + col] = f2bf(acc1[c][j]);
      }
    }
  }
}

// ================= fused CSR attention + node epilogue =================
// one wave per dst node; lane covers dims 2*lane, 2*lane+1; head = lane>>4
__global__ __launch_bounds__(256) void csr_attn(
    const int* __restrict__ rowstart, const int* __restrict__ srcs,
    const unsigned short* __restrict__ e,   // [E][128] in dst-sorted order
    const unsigned short* __restrict__ q, const unsigned short* __restrict__ k,
    const unsigned short* __restrict__ v, const unsigned short* __restrict__ xr,
    const float* __restrict__ Wb, const float* __restrict__ lng, const float* __restrict__ lnb,
    const unsigned short* __restrict__ prev, unsigned short* __restrict__ hout)
{
  const int n = blockIdx.x * 4 + (threadIdx.x >> 6);
  if (n >= NN) return;
  const int lane = threadIdx.x & 63;
  const int d0 = lane * 2;
  const size_t base = (size_t)n * 128 + d0;

  const unsigned int qp = *(const unsigned int*)(q + base);
  const float q0 = bf2f(qp & 0xffff), q1 = bf2f(qp >> 16);

  float acc0 = 0.f, acc1 = 0.f, den = 0.f;
  const int s = rowstart[n], eend = rowstart[n + 1];
  const float scale = 0.17677669529663687f;   // 1/sqrt(32)

  int pos = s;
  for (; pos + 1 < eend; pos += 2) {
    const int srcA = srcs[pos], srcB = srcs[pos + 1];
    const unsigned int kpA = *(const unsigned int*)(k + (size_t)srcA * 128 + d0);
    const unsigned int epA = *(const unsigned int*)(e + (size_t)pos * 128 + d0);
    const unsigned int vpA = *(const unsigned int*)(v + (size_t)srcA * 128 + d0);
    const unsigned int kpB = *(const unsigned int*)(k + (size_t)srcB * 128 + d0);
    const unsigned int epB = *(const unsigned int*)(e + (size_t)(pos + 1) * 128 + d0);
    const unsigned int vpB = *(const unsigned int*)(v + (size_t)srcB * 128 + d0);

    const float eA0 = bf2f(epA & 0xffff), eA1 = bf2f(epA >> 16);
    const float eB0 = bf2f(epB & 0xffff), eB1 = bf2f(epB >> 16);
    float dotA = q0 * (bf2f(kpA & 0xffff) + eA0) + q1 * (bf2f(kpA >> 16) + eA1);
    float dotB = q0 * (bf2f(kpB & 0xffff) + eB0) + q1 * (bf2f(kpB >> 16) + eB1);
    dotA += __shfl_xor(dotA, 1, 64); dotB += __shfl_xor(dotB, 1, 64);
    dotA += __shfl_xor(dotA, 2, 64); dotB += __shfl_xor(dotB, 2, 64);
    dotA += __shfl_xor(dotA, 4, 64); dotB += __shfl_xor(dotB, 4, 64);
    dotA += __shfl_xor(dotA, 8, 64); dotB += __shfl_xor(dotB, 8, 64);
    const float pA = expf(dotA * scale);
    const float pB = expf(dotB * scale);
    acc0 += pA * (bf2f(vpA & 0xffff) + eA0) + pB * (bf2f(vpB & 0xffff) + eB0);
    acc1 += pA * (bf2f(vpA >> 16) + eA1) + pB * (bf2f(vpB >> 16) + eB1);
    den  += pA + pB;
  }
  if (pos < eend) {
    const int srcA = srcs[pos];
    const unsigned int kpA = *(const unsigned int*)(k + (size_t)srcA * 128 + d0);
    const unsigned int epA = *(const unsigned int*)(e + (size_t)pos * 128 + d0);
    const unsigned int vpA = *(const unsigned int*)(v + (size_t)srcA * 128 + d0);
    const float eA0 = bf2f(epA & 0xffff), eA1 = bf2f(epA >> 16);
    float dotA = q0 * (bf2f(kpA & 0xffff) + eA0) + q1 * (bf2f(kpA >> 16) + eA1);
    dotA += __shfl_xor(dotA, 1, 64);
    dotA += __shfl_xor(dotA, 2, 64);
    dotA += __shfl_xor(dotA, 4, 64);
    dotA += __shfl_xor(dotA, 8, 64);
    const float pA = expf(dotA * scale);
    acc0 += pA * (bf2f(vpA & 0xffff) + eA0);
    acc1 += pA * (bf2f(vpA >> 16) + eA1);
    den  += pA;
  }

  const float dinv = 1.f / (den + 1e-16f);
  const float o0 = acc0 * dinv, o1 = acc1 * dinv;

  // ---- fused node epilogue ----
  const float x0 = bf2f(xr[base]), x1 = bf2f(xr[base + 1]);
  float sb = o0 * Wb[d0] + o1 * Wb[d0 + 1]
           + x0 * Wb[128 + d0] + x1 * Wb[129 + d0]
           + (o0 - x0) * Wb[256 + d0] + (o1 - x1) * Wb[257 + d0];
  #pragma unroll
  for (int off = 32; off >= 1; off >>= 1) sb += __shfl_xor(sb, off, 64);
  const float beta = 1.f / (1.f + expf(-sb));

  float y0 = beta * x0 + (1.f - beta) * o0;
  float y1 = beta * x1 + (1.f - beta) * o1;
  y0 = 0.5f * y0 * (1.f + erff(y0 * 0.7071067811865475f));
  y1 = 0.5f * y1 * (1.f + erff(y1 * 0.7071067811865475f));

  float mu = y0 + y1;
  #pragma unroll
  for (int off = 32; off >= 1; off >>= 1) mu += __shfl_xor(mu, off, 64);
  mu *= (1.f / 128.f);
  float dv0 = y0 - mu, dv1 = y1 - mu;
  float var = dv0 * dv0 + dv1 * dv1;
  #pragma unroll
  for (int off = 32; off >= 1; off >>= 1) var += __shfl_xor(var, off, 64);
  var *= (1.f / 128.f);
  const float rs = rsqrtf(var + 1e-5f);

  float h0 = dv0 * rs * lng[d0] + lnb[d0];
  float h1 = dv1 * rs * lng[d0 + 1] + lnb[d0 + 1];
  if (prev) { h0 += bf2f(prev[base]); h1 += bf2f(prev[base + 1]); }
  unsigned int packed = (unsigned int)f2bf(h0) | ((unsigned int)f2bf(h1) << 16);
  *(unsigned int*)(hout + base) = packed;
}

// ================= gate =================
__global__ __launch_bounds__(256) void gate_kernel(
    const float* __restrict__ x, const float* __restrict__ Wg,
    const float* __restrict__ bg, float* __restrict__ g)
{
  const int row = blockIdx.x * 4 + (threadIdx.x >> 6);
  const int lane = threadIdx.x & 63;
  const size_t base = (size_t)row * 128 + lane * 2;
  float s = x[base] * Wg[lane * 2] + x[base + 1] * Wg[lane * 2 + 1];
  #pragma unroll
  for (int off = 32; off >= 1; off >>= 1) s += __shfl_xor(s, off, 64);
  g[row] = 1.f / (1.f + expf(-(s + bg[0])));
}

// ================= final: out = g*x + (1-g)*((h1+h2) @ Wo + bo) =================
__global__ __launch_bounds__(256) void final_gemm(
    const unsigned short* __restrict__ A, const unsigned short* __restrict__ wT,
    const float* __restrict__ bo, const float* __restrict__ xin,
    const float* __restrict__ g, float* __restrict__ out, int M)
{
  const int wave = threadIdx.x >> 6, lane = threadIdx.x & 63;
  const int row0 = blockIdx.x * 64 + wave * 16;
  int arow = row0 + (lane & 15);
  if (arow > M - 1) arow = M - 1;
  const int kgrp = (lane >> 4) * 8;

  f32x4 acc[8];
  #pragma unroll
  for (int c = 0; c < 8; c++)
    #pragma unroll
    for (int j = 0; j < 4; j++) acc[c][j] = 0.f;

  const unsigned short* wt = wT + (size_t)10 * 16384;
  #pragma unroll
  for (int kt = 0; kt < 4; ++kt) {
    const int kb = kt * 32 + kgrp;
    short8 a = *(const short8*)(A + (size_t)arow * 128 + kb);
    #pragma unroll
    for (int c = 0; c < 8; ++c) {
      const int col = c * 16 + (lane & 15);
      short8 b = *(const short8*)(wt + (size_t)col * 128 + kb);
      acc[c] = __builtin_amdgcn_mfma_f32_16x16x32_bf16(a, b, acc[c], 0, 0, 0);
    }
  }

  const int colb = lane & 15;
  const int rsub = (lane >> 4) * 4;
  float grow[4];
  #pragma unroll
  for (int j = 0; j < 4; j++) {
    const int row = row0 + rsub + j;
    grow[j] = (row < M) ? g[row] : 0.f;
  }
  #pragma unroll
  for (int c = 0; c < 8; c++) {
    const int col = c * 16 + colb;
    const float bia = bo[col];
    #pragma unroll
    for (int j = 0; j < 4; j++) {
      const int row = row0 + rsub + j;
      if (row < M) {
        const float o = acc[c][j] + bia;
        out[(size_t)row * 128 + col] = grow[j] * xin[(size_t)row * 128 + col] + (1.f - grow[j]) * o;
      }
    }
  }
}

extern "C" void kernel_launch(void* const* d_in, const int* in_sizes, int n_in,
                              void* d_out, int out_size, void* d_ws, size_t ws_size,
                              hipStream_t stream)
{
  const float* x  = (const float*)d_in[0];
  const int*   ei = (const int*)d_in[1];
  const float* ea = (const float*)d_in[2];
  const float* Wq = (const float*)d_in[3];
  const float* bq = (const float*)d_in[4];
  const float* Wk = (const float*)d_in[5];
  const float* bk = (const float*)d_in[6];
  const float* Wv = (const float*)d_in[7];
  const float* bv = (const float*)d_in[8];
  const float* We = (const float*)d_in[9];
  const float* Ws = (const float*)d_in[10];
  const float* bs = (const float*)d_in[11];
  const float* Wb = (const float*)d_in[12];
  const float* lng= (const float*)d_in[13];
  const float* lnb= (const float*)d_in[14];
  const float* Wo = (const float*)d_in[15];
  const float* bo = (const float*)d_in[16];
  const float* Wg = (const float*)d_in[17];
  const float* bg = (const float*)d_in[18];
  float* outp = (float*)d_out;

  char* p = (char*)d_ws;
  auto take = [&](size_t b) -> char* { char* r = p; p += (b + 255) & ~(size_t)255; return r; };
  unsigned short* wT = (unsigned short*)take((size_t)11 * 16384 * 2);
  unsigned short* q  = (unsigned short*)take((size_t)NN * 128 * 2);
  unsigned short* k  = (unsigned short*)take((size_t)NN * 128 * 2);
  unsigned short* v  = (unsigned short*)take((size_t)NN * 128 * 2);
  unsigned short* xr = (unsigned short*)take((size_t)NN * 128 * 2);
  unsigned short* h1 = (unsigned short*)take((size_t)NN * 128 * 2);
  unsigned short* hs = (unsigned short*)take((size_t)NN * 128 * 2);
  float* gbuf = (float*)take((size_t)NN * 4);
  int* deg      = (int*)take((size_t)NN * 4);
  int* rowstart = (int*)take((size_t)(NN + 1) * 4);
  int* cursor   = (int*)take((size_t)NN * 4);
  int* bsum     = (int*)take((size_t)128 * 4);
  int* sortpos  = (int*)take((size_t)NE * 4);
  int* srcs     = (int*)take((size_t)NE * 4);
  unsigned short* e0 = (unsigned short*)take((size_t)NE * 128 * 2);
  size_t used = (size_t)(p - (char*)d_ws);
  const bool dual = (used + (size_t)NE * 128 * 2) <= ws_size;
  unsigned short* e1 = dual ? (unsigned short*)take((size_t)NE * 128 * 2) : e0;

  const int SCAN_BLOCKS = (NN + 1023) / 1024;   // 98

  // ---- CSR build ----
  hipMemsetAsync(deg, 0, (size_t)NN * 4, stream);
  hist_k<<<(NE + 255) / 256, 256, 0, stream>>>(ei, deg);
  scan1<<<SCAN_BLOCKS, 256, 0, stream>>>(deg, bsum);
  scan2<<<1, 64, 0, stream>>>(bsum, SCAN_BLOCKS, rowstart);
  scan3<<<SCAN_BLOCKS, 256, 0, stream>>>(deg, bsum, rowstart, cursor);
  scatter_k<<<(NE + 255) / 256, 256, 0, stream>>>(ei, cursor, sortpos, srcs);

  // ---- weights + edge projection ----
  conv_w<<<704, 256, 0, stream>>>(Wq, Wk, Wv, Ws, We, Wo, wT);
  if (dual) edge_gemm<<<12500, 256, 0, stream>>>(ea, wT, 8, 9, sortpos, e0, e1, NE);
  else      edge_gemm<<<12500, 256, 0, stream>>>(ea, wT, 8, -1, sortpos, e0, nullptr, NE);

  // ---- layer 1 ----
  qkvs_gemm<0><<<1563, 256, 0, stream>>>(x, wT, 0, bq, bk, bv, bs, q, k, v, xr, NN);
  csr_attn<<<25000, 256, 0, stream>>>(rowstart, srcs, e0, q, k, v, xr, Wb, lng, lnb, nullptr, h1);

  // ---- layer 2 ----
  if (!dual) edge_gemm<<<12500, 256, 0, stream>>>(ea, wT, 9, -1, sortpos, e0, nullptr, NE);
  qkvs_gemm<1><<<1563, 256, 0, stream>>>(h1, wT, 4, bq + 128, bk + 128, bv + 128, bs + 128, q, k, v, xr, NN);
  csr_attn<<<25000, 256, 0, stream>>>(rowstart, srcs, e1, q, k, v, xr, Wb + 384, lng + 128, lnb + 128, h1, hs);

  // ---- final ----
  gate_kernel<<<25000, 256, 0, stream>>>(x, Wg, bg, gbuf);
  final_gemm<<<1563, 256, 0, stream>>>(hs, wT, bo, x, gbuf, outp, NN);
}

// Round 3
// 1181.435 us; speedup vs baseline: 6.1274x; 1.5698x over previous
//
#include <hip/hip_runtime.h>
#include <math.h>

#define NN 100000
#define NE 800000
// DIM=128, HEADS=4, CH=32

typedef __attribute__((ext_vector_type(8))) short short8;
typedef __attribute__((ext_vector_type(4))) float f32x4;

__device__ __forceinline__ float bf2f(unsigned short u) {
  union { float f; unsigned int i; } x; x.i = ((unsigned int)u) << 16; return x.f;
}
__device__ __forceinline__ unsigned short f2bf(float f) {
  union { float f; unsigned int i; } x; x.f = f;
  unsigned int r = x.i + 0x7fffu + ((x.i >> 16) & 1u);
  return (unsigned short)(r >> 16);
}

__device__ __forceinline__ short8 load8_f32_as_bf16(const float* p) {
  const float4 a = *(const float4*)p;
  const float4 b = *(const float4*)(p + 4);
  short8 r;
  r[0] = (short)f2bf(a.x); r[1] = (short)f2bf(a.y); r[2] = (short)f2bf(a.z); r[3] = (short)f2bf(a.w);
  r[4] = (short)f2bf(b.x); r[5] = (short)f2bf(b.y); r[6] = (short)f2bf(b.z); r[7] = (short)f2bf(b.w);
  return r;
}

// ================= CSR build =================
__global__ __launch_bounds__(256) void hist_k(const int* __restrict__ ei, int* __restrict__ deg) {
  int t = blockIdx.x * 256 + threadIdx.x;
  if (t < NE) atomicAdd(&deg[ei[NE + t]], 1);
}

__global__ __launch_bounds__(256) void scan1(const int* __restrict__ deg, int* __restrict__ bsum) {
  __shared__ int sd[256];
  const int b = blockIdx.x, t = threadIdx.x, base = b * 1024;
  int s = 0;
  #pragma unroll
  for (int i = 0; i < 4; i++) { int idx = base + t * 4 + i; if (idx < NN) s += deg[idx]; }
  sd[t] = s; __syncthreads();
  for (int off = 128; off >= 1; off >>= 1) { if (t < off) sd[t] += sd[t + off]; __syncthreads(); }
  if (t == 0) bsum[b] = sd[0];
}

__global__ void scan2(int* __restrict__ bsum, int nb, int* __restrict__ rowstart) {
  if (threadIdx.x == 0 && blockIdx.x == 0) {
    int run = 0;
    for (int i = 0; i < nb; i++) { int v = bsum[i]; bsum[i] = run; run += v; }
    rowstart[NN] = run;
  }
}

__global__ __launch_bounds__(256) void scan3(const int* __restrict__ deg, const int* __restrict__ bsum,
                                             int* __restrict__ rowstart, int* __restrict__ cursor) {
  __shared__ int sd[256];
  const int b = blockIdx.x, t = threadIdx.x, base = b * 1024;
  int vals[4]; int s = 0;
  #pragma unroll
  for (int i = 0; i < 4; i++) { int idx = base + t * 4 + i; vals[i] = (idx < NN) ? deg[idx] : 0; s += vals[i]; }
  sd[t] = s; __syncthreads();
  int excl = 0;
  for (int i = 0; i < t; i++) excl += sd[i];
  int run = bsum[b] + excl;
  #pragma unroll
  for (int i = 0; i < 4; i++) {
    int idx = base + t * 4 + i;
    if (idx < NN) { rowstart[idx] = run; cursor[idx] = run; run += vals[i]; }
  }
}

__global__ __launch_bounds__(256) void scatter_k(const int* __restrict__ ei, int* __restrict__ cursor,
                                                 int* __restrict__ sortpos, int* __restrict__ srcs) {
  int t = blockIdx.x * 256 + threadIdx.x;
  if (t >= NE) return;
  int dst = ei[NE + t];
  int pos = atomicAdd(&cursor[dst], 1);
  sortpos[t] = pos;
  srcs[pos] = ei[t];
}

// ================= weight prep =================
// slots: 0..3 = Wq0,Wk0,Wv0,Ws0 ; 4..7 = Wq1,Wk1,Wv1,Ws1 ; 8,9 = We0,We1 ; 10 = Wo
__global__ __launch_bounds__(256) void conv_w(
    const float* __restrict__ Wq, const float* __restrict__ Wk, const float* __restrict__ Wv,
    const float* __restrict__ Ws, const float* __restrict__ We, const float* __restrict__ Wo,
    unsigned short* __restrict__ wT)
{
  int idx = blockIdx.x * 256 + threadIdx.x;   // 11*16384 total
  int m = idx >> 14;
  int r = idx & 16383;
  int n = r >> 7, kk = r & 127;
  const float* src;
  switch (m) {
    case 0: src = Wq; break;
    case 1: src = Wk; break;
    case 2: src = Wv; break;
    case 3: src = Ws; break;
    case 4: src = Wq + 16384; break;
    case 5: src = Wk + 16384; break;
    case 6: src = Wv + 16384; break;
    case 7: src = Ws + 16384; break;
    case 8: src = We; break;
    case 9: src = We + 16384; break;
    default: src = Wo; break;
  }
  wT[idx] = f2bf(src[(size_t)kk * 128 + n]);
}

// ================= generic 2-output GEMM, LDS-staged coalesced stores =================
// C = A[M,128] @ wT[slot] (+bias), bf16 out, optional row scatter via sortpos.
// block = 4 waves x 16 rows; per-wave LDS tile 16 rows x 272B (pad vs bank conflicts).
template<int ABF16, int HASBIAS, int SCATTER, int NMAT>
__global__ __launch_bounds__(256, 4) void gemm2(
    const void* __restrict__ Ap, const unsigned short* __restrict__ wT, int s0, int s1,
    const float* __restrict__ bias0, const float* __restrict__ bias1,
    const int* __restrict__ sortpos,
    unsigned short* __restrict__ o0, unsigned short* __restrict__ o1, int M)
{
  __shared__ unsigned char lds[4 * 16 * 272];
  const int wave = threadIdx.x >> 6, lane = threadIdx.x & 63;
  const int row0 = blockIdx.x * 64 + wave * 16;
  unsigned char* wbase = lds + wave * (16 * 272);

  int arow = row0 + (lane & 15);
  if (arow > M - 1) arow = M - 1;
  const int kgrp = (lane >> 4) * 8;

  short8 a[4];
  #pragma unroll
  for (int kt = 0; kt < 4; ++kt) {
    const int kb = kt * 32 + kgrp;
    if (ABF16) a[kt] = *(const short8*)((const unsigned short*)Ap + (size_t)arow * 128 + kb);
    else       a[kt] = load8_f32_as_bf16((const float*)Ap + (size_t)arow * 128 + kb);
  }

  const unsigned short* w0 = wT + (size_t)s0 * 16384;
  const unsigned short* w1 = wT + (size_t)s1 * 16384;

  f32x4 acc0[8], acc1[8];
  #pragma unroll
  for (int c = 0; c < 8; c++)
    #pragma unroll
    for (int j = 0; j < 4; j++) { acc0[c][j] = 0.f; if (NMAT == 2) acc1[c][j] = 0.f; }

  #pragma unroll
  for (int c = 0; c < 8; ++c) {
    const int col = c * 16 + (lane & 15);
    short8 bf0[4], bf1[4];
    #pragma unroll
    for (int kt = 0; kt < 4; ++kt) bf0[kt] = *(const short8*)(w0 + (size_t)col * 128 + kt * 32 + kgrp);
    if (NMAT == 2) {
      #pragma unroll
      for (int kt = 0; kt < 4; ++kt) bf1[kt] = *(const short8*)(w1 + (size_t)col * 128 + kt * 32 + kgrp);
    }
    #pragma unroll
    for (int kt = 0; kt < 4; ++kt)
      acc0[c] = __builtin_amdgcn_mfma_f32_16x16x32_bf16(a[kt], bf0[kt], acc0[c], 0, 0, 0);
    if (NMAT == 2) {
      #pragma unroll
      for (int kt = 0; kt < 4; ++kt)
        acc1[c] = __builtin_amdgcn_mfma_f32_16x16x32_bf16(a[kt], bf1[kt], acc1[c], 0, 0, 0);
    }
  }

  const int colb = lane & 15;
  const int rsub = (lane >> 4) * 4;
  const int r2 = lane >> 2, seg = lane & 3;
  const int grow = row0 + r2;
  size_t orow = 0;
  if (grow < M) orow = SCATTER ? (size_t)sortpos[grow] : (size_t)grow;

  // ---- mat 0 ----
  #pragma unroll
  for (int c = 0; c < 8; ++c) {
    const float bia = HASBIAS ? bias0[c * 16 + colb] : 0.f;
    #pragma unroll
    for (int j = 0; j < 4; ++j)
      *(unsigned short*)(wbase + (rsub + j) * 272 + (c * 16 + colb) * 2) = f2bf(acc0[c][j] + bia);
  }
  __syncthreads();
  if (grow < M) {
    #pragma unroll
    for (int i = 0; i < 4; ++i) {
      short8 vv = *(const short8*)(wbase + r2 * 272 + seg * 64 + i * 16);
      *(short8*)(o0 + orow * 128 + seg * 32 + i * 8) = vv;
    }
  }
  if (NMAT == 2) {
    __syncthreads();
    #pragma unroll
    for (int c = 0; c < 8; ++c) {
      const float bia = HASBIAS ? bias1[c * 16 + colb] : 0.f;
      #pragma unroll
      for (int j = 0; j < 4; ++j)
        *(unsigned short*)(wbase + (rsub + j) * 272 + (c * 16 + colb) * 2) = f2bf(acc1[c][j] + bia);
    }
    __syncthreads();
    if (grow < M) {
      #pragma unroll
      for (int i = 0; i < 4; ++i) {
        short8 vv = *(const short8*)(wbase + r2 * 272 + seg * 64 + i * 16);
        *(short8*)(o1 + orow * 128 + seg * 32 + i * 8) = vv;
      }
    }
  }
}

// ================= fused CSR attention + node epilogue =================
__global__ __launch_bounds__(256) void csr_attn(
    const int* __restrict__ rowstart, const int* __restrict__ srcs,
    const unsigned short* __restrict__ e,   // [E][128] in dst-sorted order
    const unsigned short* __restrict__ q, const unsigned short* __restrict__ k,
    const unsigned short* __restrict__ v, const unsigned short* __restrict__ xr,
    const float* __restrict__ Wb, const float* __restrict__ lng, const float* __restrict__ lnb,
    const unsigned short* __restrict__ prev, unsigned short* __restrict__ hout)
{
  const int n = blockIdx.x * 4 + (threadIdx.x >> 6);
  if (n >= NN) return;
  const int lane = threadIdx.x & 63;
  const int d0 = lane * 2;
  const size_t base = (size_t)n * 128 + d0;

  const unsigned int qp = *(const unsigned int*)(q + base);
  const float q0 = bf2f(qp & 0xffff), q1 = bf2f(qp >> 16);

  float acc0 = 0.f, acc1 = 0.f, den = 0.f;
  const int s = rowstart[n], eend = rowstart[n + 1];
  const float scale = 0.17677669529663687f;   // 1/sqrt(32)

  int pos = s;
  for (; pos + 1 < eend; pos += 2) {
    const int srcA = srcs[pos], srcB = srcs[pos + 1];
    const unsigned int kpA = *(const unsigned int*)(k + (size_t)srcA * 128 + d0);
    const unsigned int epA = *(const unsigned int*)(e + (size_t)pos * 128 + d0);
    const unsigned int vpA = *(const unsigned int*)(v + (size_t)srcA * 128 + d0);
    const unsigned int kpB = *(const unsigned int*)(k + (size_t)srcB * 128 + d0);
    const unsigned int epB = *(const unsigned int*)(e + (size_t)(pos + 1) * 128 + d0);
    const unsigned int vpB = *(const unsigned int*)(v + (size_t)srcB * 128 + d0);

    const float eA0 = bf2f(epA & 0xffff), eA1 = bf2f(epA >> 16);
    const float eB0 = bf2f(epB & 0xffff), eB1 = bf2f(epB >> 16);
    float dotA = q0 * (bf2f(kpA & 0xffff) + eA0) + q1 * (bf2f(kpA >> 16) + eA1);
    float dotB = q0 * (bf2f(kpB & 0xffff) + eB0) + q1 * (bf2f(kpB >> 16) + eB1);
    dotA += __shfl_xor(dotA, 1, 64); dotB += __shfl_xor(dotB, 1, 64);
    dotA += __shfl_xor(dotA, 2, 64); dotB += __shfl_xor(dotB, 2, 64);
    dotA += __shfl_xor(dotA, 4, 64); dotB += __shfl_xor(dotB, 4, 64);
    dotA += __shfl_xor(dotA, 8, 64); dotB += __shfl_xor(dotB, 8, 64);
    const float pA = expf(dotA * scale);
    const float pB = expf(dotB * scale);
    acc0 += pA * (bf2f(vpA & 0xffff) + eA0) + pB * (bf2f(vpB & 0xffff) + eB0);
    acc1 += pA * (bf2f(vpA >> 16) + eA1) + pB * (bf2f(vpB >> 16) + eB1);
    den  += pA + pB;
  }
  if (pos < eend) {
    const int srcA = srcs[pos];
    const unsigned int kpA = *(const unsigned int*)(k + (size_t)srcA * 128 + d0);
    const unsigned int epA = *(const unsigned int*)(e + (size_t)pos * 128 + d0);
    const unsigned int vpA = *(const unsigned int*)(v + (size_t)srcA * 128 + d0);
    const float eA0 = bf2f(epA & 0xffff), eA1 = bf2f(epA >> 16);
    float dotA = q0 * (bf2f(kpA & 0xffff) + eA0) + q1 * (bf2f(kpA >> 16) + eA1);
    dotA += __shfl_xor(dotA, 1, 64);
    dotA += __shfl_xor(dotA, 2, 64);
    dotA += __shfl_xor(dotA, 4, 64);
    dotA += __shfl_xor(dotA, 8, 64);
    const float pA = expf(dotA * scale);
    acc0 += pA * (bf2f(vpA & 0xffff) + eA0);
    acc1 += pA * (bf2f(vpA >> 16) + eA1);
    den  += pA;
  }

  const float dinv = 1.f / (den + 1e-16f);
  const float o0 = acc0 * dinv, o1 = acc1 * dinv;

  const float x0 = bf2f(xr[base]), x1 = bf2f(xr[base + 1]);
  float sb = o0 * Wb[d0] + o1 * Wb[d0 + 1]
           + x0 * Wb[128 + d0] + x1 * Wb[129 + d0]
           + (o0 - x0) * Wb[256 + d0] + (o1 - x1) * Wb[257 + d0];
  #pragma unroll
  for (int off = 32; off >= 1; off >>= 1) sb += __shfl_xor(sb, off, 64);
  const float beta = 1.f / (1.f + expf(-sb));

  float y0 = beta * x0 + (1.f - beta) * o0;
  float y1 = beta * x1 + (1.f - beta) * o1;
  y0 = 0.5f * y0 * (1.f + erff(y0 * 0.7071067811865475f));
  y1 = 0.5f * y1 * (1.f + erff(y1 * 0.7071067811865475f));

  float mu = y0 + y1;
  #pragma unroll
  for (int off = 32; off >= 1; off >>= 1) mu += __shfl_xor(mu, off, 64);
  mu *= (1.f / 128.f);
  float dv0 = y0 - mu, dv1 = y1 - mu;
  float var = dv0 * dv0 + dv1 * dv1;
  #pragma unroll
  for (int off = 32; off >= 1; off >>= 1) var += __shfl_xor(var, off, 64);
  var *= (1.f / 128.f);
  const float rs = rsqrtf(var + 1e-5f);

  float h0 = dv0 * rs * lng[d0] + lnb[d0];
  float h1 = dv1 * rs * lng[d0 + 1] + lnb[d0 + 1];
  if (prev) { h0 += bf2f(prev[base]); h1 += bf2f(prev[base + 1]); }
  unsigned int packed = (unsigned int)f2bf(h0) | ((unsigned int)f2bf(h1) << 16);
  *(unsigned int*)(hout + base) = packed;
}

// ================= gate =================
__global__ __launch_bounds__(256) void gate_kernel(
    const float* __restrict__ x, const float* __restrict__ Wg,
    const float* __restrict__ bg, float* __restrict__ g)
{
  const int row = blockIdx.x * 4 + (threadIdx.x >> 6);
  const int lane = threadIdx.x & 63;
  const size_t base = (size_t)row * 128 + lane * 2;
  float s = x[base] * Wg[lane * 2] + x[base + 1] * Wg[lane * 2 + 1];
  #pragma unroll
  for (int off = 32; off >= 1; off >>= 1) s += __shfl_xor(s, off, 64);
  g[row] = 1.f / (1.f + expf(-(s + bg[0])));
}

// ================= final: out = g*x + (1-g)*((h1+h2) @ Wo + bo) =================
__global__ __launch_bounds__(256) void final_gemm(
    const unsigned short* __restrict__ A, const unsigned short* __restrict__ wT,
    const float* __restrict__ bo, const float* __restrict__ xin,
    const float* __restrict__ g, float* __restrict__ out, int M)
{
  const int wave = threadIdx.x >> 6, lane = threadIdx.x & 63;
  const int row0 = blockIdx.x * 64 + wave * 16;
  int arow = row0 + (lane & 15);
  if (arow > M - 1) arow = M - 1;
  const int kgrp = (lane >> 4) * 8;

  f32x4 acc[8];
  #pragma unroll
  for (int c = 0; c < 8; c++)
    #pragma unroll
    for (int j = 0; j < 4; j++) acc[c][j] = 0.f;

  const unsigned short* wt = wT + (size_t)10 * 16384;
  short8 a[4];
  #pragma unroll
  for (int kt = 0; kt < 4; ++kt)
    a[kt] = *(const short8*)(A + (size_t)arow * 128 + kt * 32 + kgrp);
  #pragma unroll
  for (int c = 0; c < 8; ++c) {
    const int col = c * 16 + (lane & 15);
    #pragma unroll
    for (int kt = 0; kt < 4; ++kt) {
      short8 b = *(const short8*)(wt + (size_t)col * 128 + kt * 32 + kgrp);
      acc[c] = __builtin_amdgcn_mfma_f32_16x16x32_bf16(a[kt], b, acc[c], 0, 0, 0);
    }
  }

  const int colb = lane & 15;
  const int rsub = (lane >> 4) * 4;
  float grow[4];
  #pragma unroll
  for (int j = 0; j < 4; j++) {
    const int row = row0 + rsub + j;
    grow[j] = (row < M) ? g[row] : 0.f;
  }
  #pragma unroll
  for (int c = 0; c < 8; c++) {
    const int col = c * 16 + colb;
    const float bia = bo[col];
    #pragma unroll
    for (int j = 0; j < 4; j++) {
      const int row = row0 + rsub + j;
      if (row < M) {
        const float o = acc[c][j] + bia;
        out[(size_t)row * 128 + col] = grow[j] * xin[(size_t)row * 128 + col] + (1.f - grow[j]) * o;
      }
    }
  }
}

extern "C" void kernel_launch(void* const* d_in, const int* in_sizes, int n_in,
                              void* d_out, int out_size, void* d_ws, size_t ws_size,
                              hipStream_t stream)
{
  const float* x  = (const float*)d_in[0];
  const int*   ei = (const int*)d_in[1];
  const float* ea = (const float*)d_in[2];
  const float* Wq = (const float*)d_in[3];
  const float* bq = (const float*)d_in[4];
  const float* Wk = (const float*)d_in[5];
  const float* bk = (const float*)d_in[6];
  const float* Wv = (const float*)d_in[7];
  const float* bv = (const float*)d_in[8];
  const float* We = (const float*)d_in[9];
  const float* Ws = (const float*)d_in[10];
  const float* bs = (const float*)d_in[11];
  const float* Wb = (const float*)d_in[12];
  const float* lng= (const float*)d_in[13];
  const float* lnb= (const float*)d_in[14];
  const float* Wo = (const float*)d_in[15];
  const float* bo = (const float*)d_in[16];
  const float* Wg = (const float*)d_in[17];
  const float* bg = (const float*)d_in[18];
  float* outp = (float*)d_out;

  char* p = (char*)d_ws;
  auto take = [&](size_t b) -> char* { char* r = p; p += (b + 255) & ~(size_t)255; return r; };
  unsigned short* wT = (unsigned short*)take((size_t)11 * 16384 * 2);
  unsigned short* q  = (unsigned short*)take((size_t)NN * 128 * 2);
  unsigned short* k  = (unsigned short*)take((size_t)NN * 128 * 2);
  unsigned short* v  = (unsigned short*)take((size_t)NN * 128 * 2);
  unsigned short* xr = (unsigned short*)take((size_t)NN * 128 * 2);
  unsigned short* h1 = (unsigned short*)take((size_t)NN * 128 * 2);
  unsigned short* hs = (unsigned short*)take((size_t)NN * 128 * 2);
  float* gbuf = (float*)take((size_t)NN * 4);
  int* deg      = (int*)take((size_t)NN * 4);
  int* rowstart = (int*)take((size_t)(NN + 1) * 4);
  int* cursor   = (int*)take((size_t)NN * 4);
  int* bsum     = (int*)take((size_t)128 * 4);
  int* sortpos  = (int*)take((size_t)NE * 4);
  int* srcs     = (int*)take((size_t)NE * 4);
  unsigned short* e0 = (unsigned short*)take((size_t)NE * 128 * 2);
  size_t used = (size_t)(p - (char*)d_ws);
  const bool dual = (used + (size_t)NE * 128 * 2) <= ws_size;
  unsigned short* e1 = dual ? (unsigned short*)take((size_t)NE * 128 * 2) : e0;

  const int SCAN_BLOCKS = (NN + 1023) / 1024;   // 98

  // ---- CSR build ----
  hipMemsetAsync(deg, 0, (size_t)NN * 4, stream);
  hist_k<<<(NE + 255) / 256, 256, 0, stream>>>(ei, deg);
  scan1<<<SCAN_BLOCKS, 256, 0, stream>>>(deg, bsum);
  scan2<<<1, 64, 0, stream>>>(bsum, SCAN_BLOCKS, rowstart);
  scan3<<<SCAN_BLOCKS, 256, 0, stream>>>(deg, bsum, rowstart, cursor);
  scatter_k<<<(NE + 255) / 256, 256, 0, stream>>>(ei, cursor, sortpos, srcs);

  // ---- weights + edge projection ----
  conv_w<<<704, 256, 0, stream>>>(Wq, Wk, Wv, Ws, We, Wo, wT);
  if (dual) {
    gemm2<0,0,1,2><<<12500, 256, 0, stream>>>(ea, wT, 8, 9, nullptr, nullptr, sortpos, e0, e1, NE);
  } else {
    gemm2<0,0,1,1><<<12500, 256, 0, stream>>>(ea, wT, 8, 8, nullptr, nullptr, sortpos, e0, e0, NE);
  }

  // ---- layer 1 ----
  gemm2<0,1,0,2><<<1563, 256, 0, stream>>>(x, wT, 0, 1, bq, bk, nullptr, q, k, NN);
  gemm2<0,1,0,2><<<1563, 256, 0, stream>>>(x, wT, 2, 3, bv, bs, nullptr, v, xr, NN);
  csr_attn<<<25000, 256, 0, stream>>>(rowstart, srcs, e0, q, k, v, xr, Wb, lng, lnb, nullptr, h1);

  // ---- layer 2 ----
  if (!dual) gemm2<0,0,1,1><<<12500, 256, 0, stream>>>(ea, wT, 9, 9, nullptr, nullptr, sortpos, e0, e0, NE);
  gemm2<1,1,0,2><<<1563, 256, 0, stream>>>(h1, wT, 4, 5, bq + 128, bk + 128, nullptr, q, k, NN);
  gemm2<1,1,0,2><<<1563, 256, 0, stream>>>(h1, wT, 6, 7, bv + 128, bs + 128, nullptr, v, xr, NN);
  csr_attn<<<25000, 256, 0, stream>>>(rowstart, srcs, e1, q, k, v, xr, Wb + 384, lng + 128, lnb + 128, h1, hs);

  // ---- final ----
  gate_kernel<<<25000, 256, 0, stream>>>(x, Wg, bg, gbuf);
  final_gemm<<<1563, 256, 0, stream>>>(hs, wT, bo, x, gbuf, outp, NN);
}

// Round 4
// 944.677 us; speedup vs baseline: 7.6631x; 1.2506x over previous
//
#include <hip/hip_runtime.h>
#include <math.h>

#define NN 100000
#define NE 800000
// DIM=128, HEADS=4, CH=32

typedef __attribute__((ext_vector_type(8))) short short8;
typedef __attribute__((ext_vector_type(4))) float f32x4;

__device__ __forceinline__ float bf2f(unsigned short u) {
  union { float f; unsigned int i; } x; x.i = ((unsigned int)u) << 16; return x.f;
}
__device__ __forceinline__ unsigned short f2bf(float f) {
  union { float f; unsigned int i; } x; x.f = f;
  unsigned int r = x.i + 0x7fffu + ((x.i >> 16) & 1u);
  return (unsigned short)(r >> 16);
}

__device__ __forceinline__ short8 load8_f32_as_bf16(const float* p) {
  const float4 a = *(const float4*)p;
  const float4 b = *(const float4*)(p + 4);
  short8 r;
  r[0] = (short)f2bf(a.x); r[1] = (short)f2bf(a.y); r[2] = (short)f2bf(a.z); r[3] = (short)f2bf(a.w);
  r[4] = (short)f2bf(b.x); r[5] = (short)f2bf(b.y); r[6] = (short)f2bf(b.z); r[7] = (short)f2bf(b.w);
  return r;
}

// ================= CSR build =================
__global__ __launch_bounds__(256) void hist_k(const int* __restrict__ ei, int* __restrict__ deg) {
  int t = blockIdx.x * 256 + threadIdx.x;
  if (t < NE) atomicAdd(&deg[ei[NE + t]], 1);
}

__global__ __launch_bounds__(256) void scan1(const int* __restrict__ deg, int* __restrict__ bsum) {
  __shared__ int sd[256];
  const int b = blockIdx.x, t = threadIdx.x, base = b * 1024;
  int s = 0;
  #pragma unroll
  for (int i = 0; i < 4; i++) { int idx = base + t * 4 + i; if (idx < NN) s += deg[idx]; }
  sd[t] = s; __syncthreads();
  for (int off = 128; off >= 1; off >>= 1) { if (t < off) sd[t] += sd[t + off]; __syncthreads(); }
  if (t == 0) bsum[b] = sd[0];
}

__global__ void scan2(int* __restrict__ bsum, int nb, int* __restrict__ rowstart) {
  if (threadIdx.x == 0 && blockIdx.x == 0) {
    int run = 0;
    for (int i = 0; i < nb; i++) { int v = bsum[i]; bsum[i] = run; run += v; }
    rowstart[NN] = run;
  }
}

__global__ __launch_bounds__(256) void scan3(const int* __restrict__ deg, const int* __restrict__ bsum,
                                             int* __restrict__ rowstart, int* __restrict__ cursor) {
  __shared__ int sd[256];
  const int b = blockIdx.x, t = threadIdx.x, base = b * 1024;
  int vals[4]; int s = 0;
  #pragma unroll
  for (int i = 0; i < 4; i++) { int idx = base + t * 4 + i; vals[i] = (idx < NN) ? deg[idx] : 0; s += vals[i]; }
  sd[t] = s; __syncthreads();
  int excl = 0;
  for (int i = 0; i < t; i++) excl += sd[i];
  int run = bsum[b] + excl;
  #pragma unroll
  for (int i = 0; i < 4; i++) {
    int idx = base + t * 4 + i;
    if (idx < NN) { rowstart[idx] = run; cursor[idx] = run; run += vals[i]; }
  }
}

__global__ __launch_bounds__(256) void scatter_k(const int* __restrict__ ei, int* __restrict__ cursor,
                                                 int* __restrict__ sortpos, int* __restrict__ srcs) {
  int t = blockIdx.x * 256 + threadIdx.x;
  if (t >= NE) return;
  int dst = ei[NE + t];
  int pos = atomicAdd(&cursor[dst], 1);
  sortpos[t] = pos;
  srcs[pos] = ei[t];
}

// ================= weight prep =================
// slots: 0..3 = Wq0,Wk0,Wv0,Ws0 ; 4..7 = Wq1,Wk1,Wv1,Ws1 ; 8,9 = We0,We1 ; 10 = Wo
__global__ __launch_bounds__(256) void conv_w(
    const float* __restrict__ Wq, const float* __restrict__ Wk, const float* __restrict__ Wv,
    const float* __restrict__ Ws, const float* __restrict__ We, const float* __restrict__ Wo,
    unsigned short* __restrict__ wT)
{
  int idx = blockIdx.x * 256 + threadIdx.x;   // 11*16384 total
  int m = idx >> 14;
  int r = idx & 16383;
  int n = r >> 7, kk = r & 127;
  const float* src;
  switch (m) {
    case 0: src = Wq; break;
    case 1: src = Wk; break;
    case 2: src = Wv; break;
    case 3: src = Ws; break;
    case 4: src = Wq + 16384; break;
    case 5: src = Wk + 16384; break;
    case 6: src = Wv + 16384; break;
    case 7: src = Ws + 16384; break;
    case 8: src = We; break;
    case 9: src = We + 16384; break;
    default: src = Wo; break;
  }
  wT[idx] = f2bf(src[(size_t)kk * 128 + n]);
}

// ================= register-weight GEMM, swapped-operand MFMA =================
// C = A[M,128] @ wT[slot] (+bias), bf16 out, optional row scatter via sortpos.
// block = 4 waves; wave owns 32 cols (2 c-blocks); weights live in VGPRs.
// Swapped mfma(wfrag, afrag, acc): lane holds row=lane&15, cols=(lane>>4)*4+j.
template<int ABF16, int HASBIAS, int SCATTER, int NMAT>
__global__ __launch_bounds__(256, 3) void gemm_rs(
    const void* __restrict__ Ap, const unsigned short* __restrict__ wT, int s0, int s1,
    const float* __restrict__ bias0, const float* __restrict__ bias1,
    const int* __restrict__ sortpos,
    unsigned short* __restrict__ o0, unsigned short* __restrict__ o1, int M)
{
  const int wave = threadIdx.x >> 6, lane = threadIdx.x & 63;
  const int l15 = lane & 15, g = lane >> 4;
  const int colf = wave * 32;
  const int rb = blockIdx.x * 64;

  // --- preload weight fragments into registers (once) ---
  short8 wf[NMAT][2][4];
  const int slots[2] = { s0, s1 };
  #pragma unroll
  for (int m = 0; m < NMAT; ++m) {
    const unsigned short* wp = wT + (size_t)slots[m] * 16384;
    #pragma unroll
    for (int cb = 0; cb < 2; ++cb) {
      const int col = colf + cb * 16 + l15;
      #pragma unroll
      for (int kt = 0; kt < 4; ++kt)
        wf[m][cb][kt] = *(const short8*)(wp + (size_t)col * 128 + kt * 32 + g * 8);
    }
  }
  float bia[NMAT][2][4];
  if (HASBIAS) {
    const float* bp[2] = { bias0, bias1 };
    #pragma unroll
    for (int m = 0; m < NMAT; ++m)
      #pragma unroll
      for (int cb = 0; cb < 2; ++cb)
        #pragma unroll
        for (int j = 0; j < 4; ++j)
          bia[m][cb][j] = bp[m][colf + cb * 16 + g * 4 + j];
  }

  #pragma unroll
  for (int rg = 0; rg < 4; ++rg) {
    const int r = rb + rg * 16 + l15;
    const int ar = (r < M) ? r : (M - 1);
    short8 a[4];
    #pragma unroll
    for (int kt = 0; kt < 4; ++kt) {
      if (ABF16) a[kt] = *(const short8*)((const unsigned short*)Ap + (size_t)ar * 128 + kt * 32 + g * 8);
      else       a[kt] = load8_f32_as_bf16((const float*)Ap + (size_t)ar * 128 + kt * 32 + g * 8);
    }

    f32x4 accs[NMAT][2];
    #pragma unroll
    for (int m = 0; m < NMAT; ++m) {
      #pragma unroll
      for (int cb = 0; cb < 2; ++cb) {
        f32x4 acc; acc[0] = 0.f; acc[1] = 0.f; acc[2] = 0.f; acc[3] = 0.f;
        #pragma unroll
        for (int kt = 0; kt < 4; ++kt)
          acc = __builtin_amdgcn_mfma_f32_16x16x32_bf16(wf[m][cb][kt], a[kt], acc, 0, 0, 0);
        accs[m][cb] = acc;
      }
    }

    if (r < M) {
      const size_t orow = SCATTER ? (size_t)sortpos[r] : (size_t)r;
      #pragma unroll
      for (int m = 0; m < NMAT; ++m) {
        unsigned short* op = (m == 0) ? o0 : o1;
        #pragma unroll
        for (int cb = 0; cb < 2; ++cb) {
          f32x4 acc = accs[m][cb];
          float f0 = acc[0], f1 = acc[1], f2 = acc[2], f3 = acc[3];
          if (HASBIAS) { f0 += bia[m][cb][0]; f1 += bia[m][cb][1]; f2 += bia[m][cb][2]; f3 += bia[m][cb][3]; }
          uint2 pk;
          pk.x = (unsigned int)f2bf(f0) | ((unsigned int)f2bf(f1) << 16);
          pk.y = (unsigned int)f2bf(f2) | ((unsigned int)f2bf(f3) << 16);
          *(uint2*)(op + orow * 128 + colf + cb * 16 + g * 4) = pk;
        }
      }
    }
  }
}

// ================= final GEMM + gate epilogue (f32 out), same structure =================
__global__ __launch_bounds__(256, 3) void final_rs(
    const unsigned short* __restrict__ A, const unsigned short* __restrict__ wp,
    const float* __restrict__ bo, const float* __restrict__ xin,
    const float* __restrict__ gate, float* __restrict__ out, int M)
{
  const int wave = threadIdx.x >> 6, lane = threadIdx.x & 63;
  const int l15 = lane & 15, g = lane >> 4;
  const int colf = wave * 32;
  const int rb = blockIdx.x * 64;

  short8 wf[2][4];
  #pragma unroll
  for (int cb = 0; cb < 2; ++cb) {
    const int col = colf + cb * 16 + l15;
    #pragma unroll
    for (int kt = 0; kt < 4; ++kt)
      wf[cb][kt] = *(const short8*)(wp + (size_t)col * 128 + kt * 32 + g * 8);
  }
  float bia[2][4];
  #pragma unroll
  for (int cb = 0; cb < 2; ++cb)
    #pragma unroll
    for (int j = 0; j < 4; ++j)
      bia[cb][j] = bo[colf + cb * 16 + g * 4 + j];

  #pragma unroll
  for (int rg = 0; rg < 4; ++rg) {
    const int r = rb + rg * 16 + l15;
    const int ar = (r < M) ? r : (M - 1);
    short8 a[4];
    #pragma unroll
    for (int kt = 0; kt < 4; ++kt)
      a[kt] = *(const short8*)(A + (size_t)ar * 128 + kt * 32 + g * 8);

    f32x4 accs[2];
    #pragma unroll
    for (int cb = 0; cb < 2; ++cb) {
      f32x4 acc; acc[0] = 0.f; acc[1] = 0.f; acc[2] = 0.f; acc[3] = 0.f;
      #pragma unroll
      for (int kt = 0; kt < 4; ++kt)
        acc = __builtin_amdgcn_mfma_f32_16x16x32_bf16(wf[cb][kt], a[kt], acc, 0, 0, 0);
      accs[cb] = acc;
    }

    if (r < M) {
      const float gr = gate[r];
      #pragma unroll
      for (int cb = 0; cb < 2; ++cb) {
        const int c0 = colf + cb * 16 + g * 4;
        const float4 xv = *(const float4*)(xin + (size_t)r * 128 + c0);
        float4 res;
        res.x = gr * xv.x + (1.f - gr) * (accs[cb][0] + bia[cb][0]);
        res.y = gr * xv.y + (1.f - gr) * (accs[cb][1] + bia[cb][1]);
        res.z = gr * xv.z + (1.f - gr) * (accs[cb][2] + bia[cb][2]);
        res.w = gr * xv.w + (1.f - gr) * (accs[cb][3] + bia[cb][3]);
        *(float4*)(out + (size_t)r * 128 + c0) = res;
      }
    }
  }
}

// ================= fused CSR attention + node epilogue =================
__global__ __launch_bounds__(256) void csr_attn(
    const int* __restrict__ rowstart, const int* __restrict__ srcs,
    const unsigned short* __restrict__ e,   // [E][128] in dst-sorted order
    const unsigned short* __restrict__ q, const unsigned short* __restrict__ k,
    const unsigned short* __restrict__ v, const unsigned short* __restrict__ xr,
    const float* __restrict__ Wb, const float* __restrict__ lng, const float* __restrict__ lnb,
    const unsigned short* __restrict__ prev, unsigned short* __restrict__ hout)
{
  const int n = blockIdx.x * 4 + (threadIdx.x >> 6);
  if (n >= NN) return;
  const int lane = threadIdx.x & 63;
  const int d0 = lane * 2;
  const size_t base = (size_t)n * 128 + d0;

  const unsigned int qp = *(const unsigned int*)(q + base);
  const float q0 = bf2f(qp & 0xffff), q1 = bf2f(qp >> 16);

  float acc0 = 0.f, acc1 = 0.f, den = 0.f;
  const int s = rowstart[n], eend = rowstart[n + 1];
  const float scale = 0.17677669529663687f;   // 1/sqrt(32)

  int pos = s;
  for (; pos + 1 < eend; pos += 2) {
    const int srcA = srcs[pos], srcB = srcs[pos + 1];
    const unsigned int kpA = *(const unsigned int*)(k + (size_t)srcA * 128 + d0);
    const unsigned int epA = *(const unsigned int*)(e + (size_t)pos * 128 + d0);
    const unsigned int vpA = *(const unsigned int*)(v + (size_t)srcA * 128 + d0);
    const unsigned int kpB = *(const unsigned int*)(k + (size_t)srcB * 128 + d0);
    const unsigned int epB = *(const unsigned int*)(e + (size_t)(pos + 1) * 128 + d0);
    const unsigned int vpB = *(const unsigned int*)(v + (size_t)srcB * 128 + d0);

    const float eA0 = bf2f(epA & 0xffff), eA1 = bf2f(epA >> 16);
    const float eB0 = bf2f(epB & 0xffff), eB1 = bf2f(epB >> 16);
    float dotA = q0 * (bf2f(kpA & 0xffff) + eA0) + q1 * (bf2f(kpA >> 16) + eA1);
    float dotB = q0 * (bf2f(kpB & 0xffff) + eB0) + q1 * (bf2f(kpB >> 16) + eB1);
    dotA += __shfl_xor(dotA, 1, 64); dotB += __shfl_xor(dotB, 1, 64);
    dotA += __shfl_xor(dotA, 2, 64); dotB += __shfl_xor(dotB, 2, 64);
    dotA += __shfl_xor(dotA, 4, 64); dotB += __shfl_xor(dotB, 4, 64);
    dotA += __shfl_xor(dotA, 8, 64); dotB += __shfl_xor(dotB, 8, 64);
    const float pA = expf(dotA * scale);
    const float pB = expf(dotB * scale);
    acc0 += pA * (bf2f(vpA & 0xffff) + eA0) + pB * (bf2f(vpB & 0xffff) + eB0);
    acc1 += pA * (bf2f(vpA >> 16) + eA1) + pB * (bf2f(vpB >> 16) + eB1);
    den  += pA + pB;
  }
  if (pos < eend) {
    const int srcA = srcs[pos];
    const unsigned int kpA = *(const unsigned int*)(k + (size_t)srcA * 128 + d0);
    const unsigned int epA = *(const unsigned int*)(e + (size_t)pos * 128 + d0);
    const unsigned int vpA = *(const unsigned int*)(v + (size_t)srcA * 128 + d0);
    const float eA0 = bf2f(epA & 0xffff), eA1 = bf2f(epA >> 16);
    float dotA = q0 * (bf2f(kpA & 0xffff) + eA0) + q1 * (bf2f(kpA >> 16) + eA1);
    dotA += __shfl_xor(dotA, 1, 64);
    dotA += __shfl_xor(dotA, 2, 64);
    dotA += __shfl_xor(dotA, 4, 64);
    dotA += __shfl_xor(dotA, 8, 64);
    const float pA = expf(dotA * scale);
    acc0 += pA * (bf2f(vpA & 0xffff) + eA0);
    acc1 += pA * (bf2f(vpA >> 16) + eA1);
    den  += pA;
  }

  const float dinv = 1.f / (den + 1e-16f);
  const float o0 = acc0 * dinv, o1 = acc1 * dinv;

  const float x0 = bf2f(xr[base]), x1 = bf2f(xr[base + 1]);
  float sb = o0 * Wb[d0] + o1 * Wb[d0 + 1]
           + x0 * Wb[128 + d0] + x1 * Wb[129 + d0]
           + (o0 - x0) * Wb[256 + d0] + (o1 - x1) * Wb[257 + d0];
  #pragma unroll
  for (int off = 32; off >= 1; off >>= 1) sb += __shfl_xor(sb, off, 64);
  const float beta = 1.f / (1.f + expf(-sb));

  float y0 = beta * x0 + (1.f - beta) * o0;
  float y1 = beta * x1 + (1.f - beta) * o1;
  y0 = 0.5f * y0 * (1.f + erff(y0 * 0.7071067811865475f));
  y1 = 0.5f * y1 * (1.f + erff(y1 * 0.7071067811865475f));

  float mu = y0 + y1;
  #pragma unroll
  for (int off = 32; off >= 1; off >>= 1) mu += __shfl_xor(mu, off, 64);
  mu *= (1.f / 128.f);
  float dv0 = y0 - mu, dv1 = y1 - mu;
  float var = dv0 * dv0 + dv1 * dv1;
  #pragma unroll
  for (int off = 32; off >= 1; off >>= 1) var += __shfl_xor(var, off, 64);
  var *= (1.f / 128.f);
  const float rs = rsqrtf(var + 1e-5f);

  float h0 = dv0 * rs * lng[d0] + lnb[d0];
  float h1 = dv1 * rs * lng[d0 + 1] + lnb[d0 + 1];
  if (prev) { h0 += bf2f(prev[base]); h1 += bf2f(prev[base + 1]); }
  unsigned int packed = (unsigned int)f2bf(h0) | ((unsigned int)f2bf(h1) << 16);
  *(unsigned int*)(hout + base) = packed;
}

// ================= gate =================
__global__ __launch_bounds__(256) void gate_kernel(
    const float* __restrict__ x, const float* __restrict__ Wg,
    const float* __restrict__ bg, float* __restrict__ g)
{
  const int row = blockIdx.x * 4 + (threadIdx.x >> 6);
  const int lane = threadIdx.x & 63;
  const size_t base = (size_t)row * 128 + lane * 2;
  float s = x[base] * Wg[lane * 2] + x[base + 1] * Wg[lane * 2 + 1];
  #pragma unroll
  for (int off = 32; off >= 1; off >>= 1) s += __shfl_xor(s, off, 64);
  g[row] = 1.f / (1.f + expf(-(s + bg[0])));
}

extern "C" void kernel_launch(void* const* d_in, const int* in_sizes, int n_in,
                              void* d_out, int out_size, void* d_ws, size_t ws_size,
                              hipStream_t stream)
{
  const float* x  = (const float*)d_in[0];
  const int*   ei = (const int*)d_in[1];
  const float* ea = (const float*)d_in[2];
  const float* Wq = (const float*)d_in[3];
  const float* bq = (const float*)d_in[4];
  const float* Wk = (const float*)d_in[5];
  const float* bk = (const float*)d_in[6];
  const float* Wv = (const float*)d_in[7];
  const float* bv = (const float*)d_in[8];
  const float* We = (const float*)d_in[9];
  const float* Ws = (const float*)d_in[10];
  const float* bs = (const float*)d_in[11];
  const float* Wb = (const float*)d_in[12];
  const float* lng= (const float*)d_in[13];
  const float* lnb= (const float*)d_in[14];
  const float* Wo = (const float*)d_in[15];
  const float* bo = (const float*)d_in[16];
  const float* Wg = (const float*)d_in[17];
  const float* bg = (const float*)d_in[18];
  float* outp = (float*)d_out;

  char* p = (char*)d_ws;
  auto take = [&](size_t b) -> char* { char* r = p; p += (b + 255) & ~(size_t)255; return r; };
  unsigned short* wT = (unsigned short*)take((size_t)11 * 16384 * 2);
  unsigned short* q  = (unsigned short*)take((size_t)NN * 128 * 2);
  unsigned short* k  = (unsigned short*)take((size_t)NN * 128 * 2);
  unsigned short* v  = (unsigned short*)take((size_t)NN * 128 * 2);
  unsigned short* xr = (unsigned short*)take((size_t)NN * 128 * 2);
  unsigned short* h1 = (unsigned short*)take((size_t)NN * 128 * 2);
  unsigned short* hs = (unsigned short*)take((size_t)NN * 128 * 2);
  float* gbuf = (float*)take((size_t)NN * 4);
  int* deg      = (int*)take((size_t)NN * 4);
  int* rowstart = (int*)take((size_t)(NN + 1) * 4);
  int* cursor   = (int*)take((size_t)NN * 4);
  int* bsum     = (int*)take((size_t)128 * 4);
  int* sortpos  = (int*)take((size_t)NE * 4);
  int* srcs     = (int*)take((size_t)NE * 4);
  unsigned short* e0 = (unsigned short*)take((size_t)NE * 128 * 2);
  size_t used = (size_t)(p - (char*)d_ws);
  const bool dual = (used + (size_t)NE * 128 * 2) <= ws_size;
  unsigned short* e1 = dual ? (unsigned short*)take((size_t)NE * 128 * 2) : e0;

  const int SCAN_BLOCKS = (NN + 1023) / 1024;   // 98
  const int NTILE_E = NE / 64;                  // 12500
  const int NTILE_N = (NN + 63) / 64;           // 1563

  // ---- CSR build ----
  hipMemsetAsync(deg, 0, (size_t)NN * 4, stream);
  hist_k<<<(NE + 255) / 256, 256, 0, stream>>>(ei, deg);
  scan1<<<SCAN_BLOCKS, 256, 0, stream>>>(deg, bsum);
  scan2<<<1, 64, 0, stream>>>(bsum, SCAN_BLOCKS, rowstart);
  scan3<<<SCAN_BLOCKS, 256, 0, stream>>>(deg, bsum, rowstart, cursor);
  scatter_k<<<(NE + 255) / 256, 256, 0, stream>>>(ei, cursor, sortpos, srcs);

  // ---- weights + edge projection ----
  conv_w<<<704, 256, 0, stream>>>(Wq, Wk, Wv, Ws, We, Wo, wT);
  if (dual) {
    gemm_rs<0,0,1,2><<<NTILE_E, 256, 0, stream>>>(ea, wT, 8, 9, nullptr, nullptr, sortpos, e0, e1, NE);
  } else {
    gemm_rs<0,0,1,1><<<NTILE_E, 256, 0, stream>>>(ea, wT, 8, 8, nullptr, nullptr, sortpos, e0, e0, NE);
  }

  // ---- layer 1 ----
  gemm_rs<0,1,0,2><<<NTILE_N, 256, 0, stream>>>(x, wT, 0, 1, bq, bk, nullptr, q, k, NN);
  gemm_rs<0,1,0,2><<<NTILE_N, 256, 0, stream>>>(x, wT, 2, 3, bv, bs, nullptr, v, xr, NN);
  csr_attn<<<25000, 256, 0, stream>>>(rowstart, srcs, e0, q, k, v, xr, Wb, lng, lnb, nullptr, h1);

  // ---- layer 2 ----
  if (!dual) gemm_rs<0,0,1,1><<<NTILE_E, 256, 0, stream>>>(ea, wT, 9, 9, nullptr, nullptr, sortpos, e0, e0, NE);
  gemm_rs<1,1,0,2><<<NTILE_N, 256, 0, stream>>>(h1, wT, 4, 5, bq + 128, bk + 128, nullptr, q, k, NN);
  gemm_rs<1,1,0,2><<<NTILE_N, 256, 0, stream>>>(h1, wT, 6, 7, bv + 128, bs + 128, nullptr, v, xr, NN);
  csr_attn<<<25000, 256, 0, stream>>>(rowstart, srcs, e1, q, k, v, xr, Wb + 384, lng + 128, lnb + 128, h1, hs);

  // ---- final ----
  gate_kernel<<<25000, 256, 0, stream>>>(x, Wg, bg, gbuf);
  final_rs<<<NTILE_N, 256, 0, stream>>>(hs, wT + (size_t)10 * 16384, bo, x, gbuf, outp, NN);
}

// Round 7
// 916.218 us; speedup vs baseline: 7.9011x; 1.0311x over previous
//
#include <hip/hip_runtime.h>
#include <math.h>

#define NN 100000
#define NE 800000
// DIM=128, HEADS=4, CH=32

typedef __attribute__((ext_vector_type(8))) short short8;
typedef __attribute__((ext_vector_type(4))) float f32x4;

__device__ __forceinline__ float bf2f(unsigned short u) {
  union { float f; unsigned int i; } x; x.i = ((unsigned int)u) << 16; return x.f;
}
__device__ __forceinline__ unsigned short f2bf(float f) {
  union { float f; unsigned int i; } x; x.f = f;
  unsigned int r = x.i + 0x7fffu + ((x.i >> 16) & 1u);
  return (unsigned short)(r >> 16);
}

__device__ __forceinline__ short8 load8_f32_as_bf16(const float* p) {
  const float4 a = *(const float4*)p;
  const float4 b = *(const float4*)(p + 4);
  short8 r;
  r[0] = (short)f2bf(a.x); r[1] = (short)f2bf(a.y); r[2] = (short)f2bf(a.z); r[3] = (short)f2bf(a.w);
  r[4] = (short)f2bf(b.x); r[5] = (short)f2bf(b.y); r[6] = (short)f2bf(b.z); r[7] = (short)f2bf(b.w);
  return r;
}

// ================= CSR build =================
__global__ __launch_bounds__(256) void hist_k(const int* __restrict__ ei, int* __restrict__ deg) {
  int t = blockIdx.x * 256 + threadIdx.x;
  if (t < NE) atomicAdd(&deg[ei[NE + t]], 1);
}

__global__ __launch_bounds__(256) void scan1(const int* __restrict__ deg, int* __restrict__ bsum) {
  __shared__ int sd[256];
  const int b = blockIdx.x, t = threadIdx.x, base = b * 1024;
  int s = 0;
  #pragma unroll
  for (int i = 0; i < 4; i++) { int idx = base + t * 4 + i; if (idx < NN) s += deg[idx]; }
  sd[t] = s; __syncthreads();
  for (int off = 128; off >= 1; off >>= 1) { if (t < off) sd[t] += sd[t + off]; __syncthreads(); }
  if (t == 0) bsum[b] = sd[0];
}

__global__ void scan2(int* __restrict__ bsum, int nb, int* __restrict__ rowstart) {
  if (threadIdx.x == 0 && blockIdx.x == 0) {
    int run = 0;
    for (int i = 0; i < nb; i++) { int v = bsum[i]; bsum[i] = run; run += v; }
    rowstart[NN] = run;
  }
}

__global__ __launch_bounds__(256) void scan3(const int* __restrict__ deg, const int* __restrict__ bsum,
                                             int* __restrict__ rowstart, int* __restrict__ cursor) {
  __shared__ int sd[256];
  const int b = blockIdx.x, t = threadIdx.x, base = b * 1024;
  int vals[4]; int s = 0;
  #pragma unroll
  for (int i = 0; i < 4; i++) { int idx = base + t * 4 + i; vals[i] = (idx < NN) ? deg[idx] : 0; s += vals[i]; }
  sd[t] = s; __syncthreads();
  int excl = 0;
  for (int i = 0; i < t; i++) excl += sd[i];
  int run = bsum[b] + excl;
  #pragma unroll
  for (int i = 0; i < 4; i++) {
    int idx = base + t * 4 + i;
    if (idx < NN) { rowstart[idx] = run; cursor[idx] = run; run += vals[i]; }
  }
}

__global__ __launch_bounds__(256) void scatter_k(const int* __restrict__ ei, int* __restrict__ cursor,
                                                 int2* __restrict__ rec) {
  int t = blockIdx.x * 256 + threadIdx.x;
  if (t >= NE) return;
  int dst = ei[NE + t];
  int pos = atomicAdd(&cursor[dst], 1);
  rec[pos] = make_int2(ei[t], t);   // {src, edge_id}
}

// ================= weight prep =================
// slots: 0..3 = Wq0,Wk0,Wv0,Ws0 ; 4..7 = Wq1,Wk1,Wv1,Ws1 ; 8,9 = We0,We1 ; 10 = Wo
__global__ __launch_bounds__(256) void conv_w(
    const float* __restrict__ Wq, const float* __restrict__ Wk, const float* __restrict__ Wv,
    const float* __restrict__ Ws, const float* __restrict__ We, const float* __restrict__ Wo,
    unsigned short* __restrict__ wT)
{
  int idx = blockIdx.x * 256 + threadIdx.x;   // 11*16384 total
  int m = idx >> 14;
  int r = idx & 16383;
  int n = r >> 7, kk = r & 127;
  const float* src;
  switch (m) {
    case 0: src = Wq; break;
    case 1: src = Wk; break;
    case 2: src = Wv; break;
    case 3: src = Ws; break;
    case 4: src = Wq + 16384; break;
    case 5: src = Wk + 16384; break;
    case 6: src = Wv + 16384; break;
    case 7: src = Ws + 16384; break;
    case 8: src = We; break;
    case 9: src = We + 16384; break;
    default: src = Wo; break;
  }
  wT[idx] = f2bf(src[(size_t)kk * 128 + n]);
}

// ================= register-weight GEMM, swapped-operand MFMA =================
// C = A[M,128] @ wT[slot] (+bias), bf16 out, coalesced row-order stores.
// block = 4 waves x 128 rows; wave owns 32 cols; weights live in VGPRs.
// Swapped mfma(wfrag, afrag, acc): lane holds row=lane&15, cols=(lane>>4)*4+j.
template<int ABF16, int HASBIAS, int NMAT>
__global__ __launch_bounds__(256, 2) void gemm_rs(
    const void* __restrict__ Ap, const unsigned short* __restrict__ wT, int s0, int s1,
    const float* __restrict__ bias0, const float* __restrict__ bias1,
    unsigned short* __restrict__ o0, unsigned short* __restrict__ o1, int M)
{
  const int wave = threadIdx.x >> 6, lane = threadIdx.x & 63;
  const int l15 = lane & 15, g = lane >> 4;
  const int colf = wave * 32;
  const int rb = blockIdx.x * 128;

  // --- preload weight fragments into registers (once) ---
  short8 wf[NMAT][2][4];
  const int slots[2] = { s0, s1 };
  #pragma unroll
  for (int m = 0; m < NMAT; ++m) {
    const unsigned short* wp = wT + (size_t)slots[m] * 16384;
    #pragma unroll
    for (int cb = 0; cb < 2; ++cb) {
      const int col = colf + cb * 16 + l15;
      #pragma unroll
      for (int kt = 0; kt < 4; ++kt)
        wf[m][cb][kt] = *(const short8*)(wp + (size_t)col * 128 + kt * 32 + g * 8);
    }
  }
  float bia[NMAT][2][4];
  if (HASBIAS) {
    const float* bp[2] = { bias0, bias1 };
    #pragma unroll
    for (int m = 0; m < NMAT; ++m)
      #pragma unroll
      for (int cb = 0; cb < 2; ++cb)
        #pragma unroll
        for (int j = 0; j < 4; ++j)
          bia[m][cb][j] = bp[m][colf + cb * 16 + g * 4 + j];
  }

  // --- prefetch first row-group ---
  short8 a_cur[4], a_nxt[4];
  {
    const int r = rb + l15;
    const int ar = (r < M) ? r : (M - 1);
    #pragma unroll
    for (int kt = 0; kt < 4; ++kt) {
      if (ABF16) a_cur[kt] = *(const short8*)((const unsigned short*)Ap + (size_t)ar * 128 + kt * 32 + g * 8);
      else       a_cur[kt] = load8_f32_as_bf16((const float*)Ap + (size_t)ar * 128 + kt * 32 + g * 8);
    }
  }
  #pragma unroll
  for (int kt = 0; kt < 4; ++kt) a_nxt[kt] = a_cur[kt];

  #pragma unroll
  for (int rg = 0; rg < 8; ++rg) {
    if (rg < 7) {
      const int rn = rb + (rg + 1) * 16 + l15;
      const int arn = (rn < M) ? rn : (M - 1);
      #pragma unroll
      for (int kt = 0; kt < 4; ++kt) {
        if (ABF16) a_nxt[kt] = *(const short8*)((const unsigned short*)Ap + (size_t)arn * 128 + kt * 32 + g * 8);
        else       a_nxt[kt] = load8_f32_as_bf16((const float*)Ap + (size_t)arn * 128 + kt * 32 + g * 8);
      }
    }

    f32x4 accs[NMAT][2];
    #pragma unroll
    for (int m = 0; m < NMAT; ++m) {
      #pragma unroll
      for (int cb = 0; cb < 2; ++cb) {
        f32x4 acc; acc[0] = 0.f; acc[1] = 0.f; acc[2] = 0.f; acc[3] = 0.f;
        #pragma unroll
        for (int kt = 0; kt < 4; ++kt)
          acc = __builtin_amdgcn_mfma_f32_16x16x32_bf16(wf[m][cb][kt], a_cur[kt], acc, 0, 0, 0);
        accs[m][cb] = acc;
      }
    }

    const int r = rb + rg * 16 + l15;
    if (r < M) {
      #pragma unroll
      for (int m = 0; m < NMAT; ++m) {
        unsigned short* op = (m == 0) ? o0 : o1;
        #pragma unroll
        for (int cb = 0; cb < 2; ++cb) {
          f32x4 acc = accs[m][cb];
          float f0 = acc[0], f1 = acc[1], f2 = acc[2], f3 = acc[3];
          if (HASBIAS) { f0 += bia[m][cb][0]; f1 += bia[m][cb][1]; f2 += bia[m][cb][2]; f3 += bia[m][cb][3]; }
          uint2 pk;
          pk.x = (unsigned int)f2bf(f0) | ((unsigned int)f2bf(f1) << 16);
          pk.y = (unsigned int)f2bf(f2) | ((unsigned int)f2bf(f3) << 16);
          *(uint2*)(op + (size_t)r * 128 + colf + cb * 16 + g * 4) = pk;
        }
      }
    }
    #pragma unroll
    for (int kt = 0; kt < 4; ++kt) a_cur[kt] = a_nxt[kt];
  }
}

// ================= final GEMM + gate epilogue (f32 out), 64 rows/block =================
__global__ __launch_bounds__(256, 3) void final_rs(
    const unsigned short* __restrict__ A, const unsigned short* __restrict__ wp,
    const float* __restrict__ bo, const float* __restrict__ xin,
    const float* __restrict__ gate, float* __restrict__ out, int M)
{
  const int wave = threadIdx.x >> 6, lane = threadIdx.x & 63;
  const int l15 = lane & 15, g = lane >> 4;
  const int colf = wave * 32;
  const int rb = blockIdx.x * 64;

  short8 wf[2][4];
  #pragma unroll
  for (int cb = 0; cb < 2; ++cb) {
    const int col = colf + cb * 16 + l15;
    #pragma unroll
    for (int kt = 0; kt < 4; ++kt)
      wf[cb][kt] = *(const short8*)(wp + (size_t)col * 128 + kt * 32 + g * 8);
  }
  float bia[2][4];
  #pragma unroll
  for (int cb = 0; cb < 2; ++cb)
    #pragma unroll
    for (int j = 0; j < 4; ++j)
      bia[cb][j] = bo[colf + cb * 16 + g * 4 + j];

  #pragma unroll
  for (int rg = 0; rg < 4; ++rg) {
    const int r = rb + rg * 16 + l15;
    const int ar = (r < M) ? r : (M - 1);
    short8 a[4];
    #pragma unroll
    for (int kt = 0; kt < 4; ++kt)
      a[kt] = *(const short8*)(A + (size_t)ar * 128 + kt * 32 + g * 8);

    f32x4 accs[2];
    #pragma unroll
    for (int cb = 0; cb < 2; ++cb) {
      f32x4 acc; acc[0] = 0.f; acc[1] = 0.f; acc[2] = 0.f; acc[3] = 0.f;
      #pragma unroll
      for (int kt = 0; kt < 4; ++kt)
        acc = __builtin_amdgcn_mfma_f32_16x16x32_bf16(wf[cb][kt], a[kt], acc, 0, 0, 0);
      accs[cb] = acc;
    }

    if (r < M) {
      const float gr = gate[r];
      #pragma unroll
      for (int cb = 0; cb < 2; ++cb) {
        const int c0 = colf + cb * 16 + g * 4;
        const float4 xv = *(const float4*)(xin + (size_t)r * 128 + c0);
        float4 res;
        res.x = gr * xv.x + (1.f - gr) * (accs[cb][0] + bia[cb][0]);
        res.y = gr * xv.y + (1.f - gr) * (accs[cb][1] + bia[cb][1]);
        res.z = gr * xv.z + (1.f - gr) * (accs[cb][2] + bia[cb][2]);
        res.w = gr * xv.w + (1.f - gr) * (accs[cb][3] + bia[cb][3]);
        *(float4*)(out + (size_t)r * 128 + c0) = res;
      }
    }
  }
}

// ================= fused CSR attention + node epilogue =================
// e stays in edge order; rec[pos] = {src, edge_id} sorted by dst.
__global__ __launch_bounds__(256) void csr_attn(
    const int* __restrict__ rowstart, const int2* __restrict__ rec,
    const unsigned short* __restrict__ e,
    const unsigned short* __restrict__ q, const unsigned short* __restrict__ k,
    const unsigned short* __restrict__ v, const unsigned short* __restrict__ xr,
    const float* __restrict__ Wb, const float* __restrict__ lng, const float* __restrict__ lnb,
    const unsigned short* __restrict__ prev, unsigned short* __restrict__ hout)
{
  const int n = blockIdx.x * 4 + (threadIdx.x >> 6);
  if (n >= NN) return;
  const int lane = threadIdx.x & 63;
  const int d0 = lane * 2;
  const size_t base = (size_t)n * 128 + d0;

  const unsigned int qp = *(const unsigned int*)(q + base);
  const float q0 = bf2f(qp & 0xffff), q1 = bf2f(qp >> 16);

  float acc0 = 0.f, acc1 = 0.f, den = 0.f;
  const int s = rowstart[n], eend = rowstart[n + 1];
  const float scale = 0.17677669529663687f;   // 1/sqrt(32)

  int pos = s;
  for (; pos + 1 < eend; pos += 2) {
    const int2 rA = rec[pos], rB = rec[pos + 1];
    const unsigned int kpA = *(const unsigned int*)(k + (size_t)rA.x * 128 + d0);
    const unsigned int epA = *(const unsigned int*)(e + (size_t)rA.y * 128 + d0);
    const unsigned int vpA = *(const unsigned int*)(v + (size_t)rA.x * 128 + d0);
    const unsigned int kpB = *(const unsigned int*)(k + (size_t)rB.x * 128 + d0);
    const unsigned int epB = *(const unsigned int*)(e + (size_t)rB.y * 128 + d0);
    const unsigned int vpB = *(const unsigned int*)(v + (size_t)rB.x * 128 + d0);

    const float eA0 = bf2f(epA & 0xffff), eA1 = bf2f(epA >> 16);
    const float eB0 = bf2f(epB & 0xffff), eB1 = bf2f(epB >> 16);
    float dotA = q0 * (bf2f(kpA & 0xffff) + eA0) + q1 * (bf2f(kpA >> 16) + eA1);
    float dotB = q0 * (bf2f(kpB & 0xffff) + eB0) + q1 * (bf2f(kpB >> 16) + eB1);
    dotA += __shfl_xor(dotA, 1, 64); dotB += __shfl_xor(dotB, 1, 64);
    dotA += __shfl_xor(dotA, 2, 64); dotB += __shfl_xor(dotB, 2, 64);
    dotA += __shfl_xor(dotA, 4, 64); dotB += __shfl_xor(dotB, 4, 64);
    dotA += __shfl_xor(dotA, 8, 64); dotB += __shfl_xor(dotB, 8, 64);
    const float pA = expf(dotA * scale);
    const float pB = expf(dotB * scale);
    acc0 += pA * (bf2f(vpA & 0xffff) + eA0) + pB * (bf2f(vpB & 0xffff) + eB0);
    acc1 += pA * (bf2f(vpA >> 16) + eA1) + pB * (bf2f(vpB >> 16) + eB1);
    den  += pA + pB;
  }
  if (pos < eend) {
    const int2 rA = rec[pos];
    const unsigned int kpA = *(const unsigned int*)(k + (size_t)rA.x * 128 + d0);
    const unsigned int epA = *(const unsigned int*)(e + (size_t)rA.y * 128 + d0);
    const unsigned int vpA = *(const unsigned int*)(v + (size_t)rA.x * 128 + d0);
    const float eA0 = bf2f(epA & 0xffff), eA1 = bf2f(epA >> 16);
    float dotA = q0 * (bf2f(kpA & 0xffff) + eA0) + q1 * (bf2f(kpA >> 16) + eA1);
    dotA += __shfl_xor(dotA, 1, 64);
    dotA += __shfl_xor(dotA, 2, 64);
    dotA += __shfl_xor(dotA, 4, 64);
    dotA += __shfl_xor(dotA, 8, 64);
    const float pA = expf(dotA * scale);
    acc0 += pA * (bf2f(vpA & 0xffff) + eA0);
    acc1 += pA * (bf2f(vpA >> 16) + eA1);
    den  += pA;
  }

  const float dinv = 1.f / (den + 1e-16f);
  const float o0 = acc0 * dinv, o1 = acc1 * dinv;

  const float x0 = bf2f(xr[base]), x1 = bf2f(xr[base + 1]);
  float sb = o0 * Wb[d0] + o1 * Wb[d0 + 1]
           + x0 * Wb[128 + d0] + x1 * Wb[129 + d0]
           + (o0 - x0) * Wb[256 + d0] + (o1 - x1) * Wb[257 + d0];
  #pragma unroll
  for (int off = 32; off >= 1; off >>= 1) sb += __shfl_xor(sb, off, 64);
  const float beta = 1.f / (1.f + expf(-sb));

  float y0 = beta * x0 + (1.f - beta) * o0;
  float y1 = beta * x1 + (1.f - beta) * o1;
  y0 = 0.5f * y0 * (1.f + erff(y0 * 0.7071067811865475f));
  y1 = 0.5f * y1 * (1.f + erff(y1 * 0.7071067811865475f));

  float mu = y0 + y1;
  #pragma unroll
  for (int off = 32; off >= 1; off >>= 1) mu += __shfl_xor(mu, off, 64);
  mu *= (1.f / 128.f);
  float dv0 = y0 - mu, dv1 = y1 - mu;
  float var = dv0 * dv0 + dv1 * dv1;
  #pragma unroll
  for (int off = 32; off >= 1; off >>= 1) var += __shfl_xor(var, off, 64);
  var *= (1.f / 128.f);
  const float rs = rsqrtf(var + 1e-5f);

  float h0 = dv0 * rs * lng[d0] + lnb[d0];
  float h1 = dv1 * rs * lng[d0 + 1] + lnb[d0 + 1];
  if (prev) { h0 += bf2f(prev[base]); h1 += bf2f(prev[base + 1]); }
  unsigned int packed = (unsigned int)f2bf(h0) | ((unsigned int)f2bf(h1) << 16);
  *(unsigned int*)(hout + base) = packed;
}

// ================= gate =================
__global__ __launch_bounds__(256) void gate_kernel(
    const float* __restrict__ x, const float* __restrict__ Wg,
    const float* __restrict__ bg, float* __restrict__ g)
{
  const int row = blockIdx.x * 4 + (threadIdx.x >> 6);
  const int lane = threadIdx.x & 63;
  const size_t base = (size_t)row * 128 + lane * 2;
  float s = x[base] * Wg[lane * 2] + x[base + 1] * Wg[lane * 2 + 1];
  #pragma unroll
  for (int off = 32; off >= 1; off >>= 1) s += __shfl_xor(s, off, 64);
  g[row] = 1.f / (1.f + expf(-(s + bg[0])));
}

extern "C" void kernel_launch(void* const* d_in, const int* in_sizes, int n_in,
                              void* d_out, int out_size, void* d_ws, size_t ws_size,
                              hipStream_t stream)
{
  const float* x  = (const float*)d_in[0];
  const int*   ei = (const int*)d_in[1];
  const float* ea = (const float*)d_in[2];
  const float* Wq = (const float*)d_in[3];
  const float* bq = (const float*)d_in[4];
  const float* Wk = (const float*)d_in[5];
  const float* bk = (const float*)d_in[6];
  const float* Wv = (const float*)d_in[7];
  const float* bv = (const float*)d_in[8];
  const float* We = (const float*)d_in[9];
  const float* Ws = (const float*)d_in[10];
  const float* bs = (const float*)d_in[11];
  const float* Wb = (const float*)d_in[12];
  const float* lng= (const float*)d_in[13];
  const float* lnb= (const float*)d_in[14];
  const float* Wo = (const float*)d_in[15];
  const float* bo = (const float*)d_in[16];
  const float* Wg = (const float*)d_in[17];
  const float* bg = (const float*)d_in[18];
  float* outp = (float*)d_out;

  char* p = (char*)d_ws;
  auto take = [&](size_t b) -> char* { char* r = p; p += (b + 255) & ~(size_t)255; return r; };
  unsigned short* wT = (unsigned short*)take((size_t)11 * 16384 * 2);
  unsigned short* q  = (unsigned short*)take((size_t)NN * 128 * 2);
  unsigned short* k  = (unsigned short*)take((size_t)NN * 128 * 2);
  unsigned short* v  = (unsigned short*)take((size_t)NN * 128 * 2);
  unsigned short* xr = (unsigned short*)take((size_t)NN * 128 * 2);
  unsigned short* h1 = (unsigned short*)take((size_t)NN * 128 * 2);
  unsigned short* hs = (unsigned short*)take((size_t)NN * 128 * 2);
  float* gbuf = (float*)take((size_t)NN * 4);
  int* deg      = (int*)take((size_t)NN * 4);
  int* rowstart = (int*)take((size_t)(NN + 1) * 4);
  int* cursor   = (int*)take((size_t)NN * 4);
  int* bsum     = (int*)take((size_t)128 * 4);
  int2* rec     = (int2*)take((size_t)NE * 8);
  unsigned short* e0 = (unsigned short*)take((size_t)NE * 128 * 2);
  size_t used = (size_t)(p - (char*)d_ws);
  const bool dual = (used + (size_t)NE * 128 * 2) <= ws_size;
  unsigned short* e1 = dual ? (unsigned short*)take((size_t)NE * 128 * 2) : e0;

  const int SCAN_BLOCKS = (NN + 1023) / 1024;   // 98
  const int NTILE_E  = (NE + 127) / 128;        // 6250   (gemm_rs: 128 rows/block)
  const int NTILE_N  = (NN + 127) / 128;        // 782    (gemm_rs: 128 rows/block)
  const int NTILE_N64 = (NN + 63) / 64;         // 1563   (final_rs: 64 rows/block)

  // ---- CSR build ----
  hipMemsetAsync(deg, 0, (size_t)NN * 4, stream);
  hist_k<<<(NE + 255) / 256, 256, 0, stream>>>(ei, deg);
  scan1<<<SCAN_BLOCKS, 256, 0, stream>>>(deg, bsum);
  scan2<<<1, 64, 0, stream>>>(bsum, SCAN_BLOCKS, rowstart);
  scan3<<<SCAN_BLOCKS, 256, 0, stream>>>(deg, bsum, rowstart, cursor);
  scatter_k<<<(NE + 255) / 256, 256, 0, stream>>>(ei, cursor, rec);

  // ---- weights + edge projection (coalesced, edge order) ----
  conv_w<<<704, 256, 0, stream>>>(Wq, Wk, Wv, Ws, We, Wo, wT);
  if (dual) {
    gemm_rs<0,0,2><<<NTILE_E, 256, 0, stream>>>(ea, wT, 8, 9, nullptr, nullptr, e0, e1, NE);
  } else {
    gemm_rs<0,0,1><<<NTILE_E, 256, 0, stream>>>(ea, wT, 8, 8, nullptr, nullptr, e0, e0, NE);
  }

  // ---- layer 1 ----
  gemm_rs<0,1,2><<<NTILE_N, 256, 0, stream>>>(x, wT, 0, 1, bq, bk, q, k, NN);
  gemm_rs<0,1,2><<<NTILE_N, 256, 0, stream>>>(x, wT, 2, 3, bv, bs, v, xr, NN);
  csr_attn<<<25000, 256, 0, stream>>>(rowstart, rec, e0, q, k, v, xr, Wb, lng, lnb, nullptr, h1);

  // ---- layer 2 ----
  if (!dual) gemm_rs<0,0,1><<<NTILE_E, 256, 0, stream>>>(ea, wT, 9, 9, nullptr, nullptr, e0, e0, NE);
  gemm_rs<1,1,2><<<NTILE_N, 256, 0, stream>>>(h1, wT, 4, 5, bq + 128, bk + 128, q, k, NN);
  gemm_rs<1,1,2><<<NTILE_N, 256, 0, stream>>>(h1, wT, 6, 7, bv + 128, bs + 128, v, xr, NN);
  csr_attn<<<25000, 256, 0, stream>>>(rowstart, rec, e1, q, k, v, xr, Wb + 384, lng + 128, lnb + 128, h1, hs);

  // ---- final ----
  gate_kernel<<<25000, 256, 0, stream>>>(x, Wg, bg, gbuf);
  final_rs<<<NTILE_N64, 256, 0, stream>>>(hs, wT + (size_t)10 * 16384, bo, x, gbuf, outp, NN);
}